// Round 2
// baseline (4380.204 us; speedup 1.0000x reference)
//
#include <hip/hip_runtime.h>
#include <cstddef>

#define BB   8
#define VV   25
#define TT   128
#define CC   256
#define NHH  8
#define DKK  32
#define DFFF 1024
#define ITER 4
#define NN   (BB*VV)     // 200
#define LL1  (TT+1)      // 129
#define EPS_LN 1e-6f
#define EPS_BN 1e-5f
#define SLOPE  0.01f
#define SCALE_F 0.17677669529663687f   // 1/sqrt(32)

// ---------------------------------------------------------------------------
// embed: embs[n,c,t] = data[b,c,v,t] (n=b*V+v); nodes=embs; relay[n,c]=mean_t
__global__ __launch_bounds__(128) void k_embed(const float* __restrict__ data,
    float* __restrict__ embs, float* __restrict__ nodes, float* __restrict__ relay)
{
    int c = blockIdx.x, n = blockIdx.y, t = threadIdx.x;
    int b = n / VV, v = n % VV;
    float val = data[(((size_t)b*CC + c)*VV + v)*TT + t];
    size_t o = ((size_t)n*CC + c)*TT + t;
    embs[o] = val; nodes[o] = val;
    float s = val;
    for (int off = 32; off; off >>= 1) s += __shfl_down(s, off);
    __shared__ float red[2];
    if ((t & 63) == 0) red[t >> 6] = s;
    __syncthreads();
    if (t == 0) relay[n*CC + c] = (red[0] + red[1]) * (1.0f / TT);
}

// ---------------------------------------------------------------------------
// LayerNorm over channel axis: per (n,t), mean/var over C (stride T)
__global__ __launch_bounds__(256) void k_layernorm(const float* __restrict__ x,
    float* __restrict__ out, const float* __restrict__ g, const float* __restrict__ b)
{
    int idx = blockIdx.x*256 + threadIdx.x;       // over N*T
    int n = idx / TT, t = idx % TT;
    const float* xp = x + ((size_t)n*CC)*TT + t;
    float s = 0.f, ss = 0.f;
    for (int c = 0; c < CC; c++) { float v = xp[(size_t)c*TT]; s += v; ss += v*v; }
    float m = s * (1.0f/CC);
    float var = ss * (1.0f/CC) - m*m; if (var < 0.f) var = 0.f;
    float rs = rsqrtf(var + EPS_LN);
    float* op = out + ((size_t)n*CC)*TT + t;
    for (int c = 0; c < CC; c++)
        op[(size_t)c*TT] = (xp[(size_t)c*TT] - m)*rs*g[c] + b[c];
}

// ---------------------------------------------------------------------------
// Generic GEMM: out[n,o,Ls*()+off+t] = act( W[o,:]*X[n,:,t] + bias[o] (+res) )
// W [OUT,K] row-major; X [N,K,L]; out [N,OUT,*] with row stride Ls, col offset off.
__global__ __launch_bounds__(256) void k_gemm(
    const float* __restrict__ W, const float* __restrict__ X,
    const float* __restrict__ bias, const float* __restrict__ res,
    float* __restrict__ out, int K, int OUT, int L, int Ls, int ofs, int do_relu)
{
    __shared__ float sW[16][68];   // [c][o], padded (write-conflict fix)
    __shared__ float sX[16][64];   // [c][t]
    int n  = blockIdx.z;
    int o0 = blockIdx.y * 64;
    int t0 = blockIdx.x * 64;
    int tid = threadIdx.x;
    int tx = tid % 16, ty = tid / 16;
    float acc[4][4] = {};
    const float* Xn = X + (size_t)n * K * L;

    for (int kc = 0; kc < K; kc += 16) {
        {   // W tile
            int c_l = tid % 16, o_l0 = tid / 16;
            #pragma unroll
            for (int r = 0; r < 4; r++) {
                int o_l = o_l0 + r*16;
                sW[c_l][o_l] = W[(size_t)(o0 + o_l)*K + kc + c_l];
            }
        }
        {   // X tile (zero-pad t >= L)
            int t_l = tid % 64, c_l0 = tid / 64;
            #pragma unroll
            for (int r = 0; r < 4; r++) {
                int c_l = c_l0 + r*4;
                int t = t0 + t_l;
                sX[c_l][t_l] = (t < L) ? Xn[(size_t)(kc + c_l)*L + t] : 0.f;
            }
        }
        __syncthreads();
        #pragma unroll
        for (int kk = 0; kk < 16; kk++) {
            float4 a = *(const float4*)&sW[kk][ty*4];
            float4 b = *(const float4*)&sX[kk][tx*4];
            acc[0][0] += a.x*b.x; acc[0][1] += a.x*b.y; acc[0][2] += a.x*b.z; acc[0][3] += a.x*b.w;
            acc[1][0] += a.y*b.x; acc[1][1] += a.y*b.y; acc[1][2] += a.y*b.z; acc[1][3] += a.y*b.w;
            acc[2][0] += a.z*b.x; acc[2][1] += a.z*b.y; acc[2][2] += a.z*b.z; acc[2][3] += a.z*b.w;
            acc[3][0] += a.w*b.x; acc[3][1] += a.w*b.y; acc[3][2] += a.w*b.z; acc[3][3] += a.w*b.w;
        }
        __syncthreads();
    }
    #pragma unroll
    for (int i = 0; i < 4; i++) {
        int o = o0 + ty*4 + i;
        float bi = bias[o];
        #pragma unroll
        for (int j = 0; j < 4; j++) {
            int t = t0 + tx*4 + j;
            if (t < L) {
                float val = acc[i][j] + bi;
                size_t oidx = ((size_t)n*OUT + o)*Ls + ofs + t;
                if (res) val += res[oidx];
                if (do_relu) val = fmaxf(val, 0.f);
                out[oidx] = val;
            }
        }
    }
}

// ---------------------------------------------------------------------------
// Small GEMM: out[(n*OUT+o)*Ls+ofs] = act( W[o,:]*X[n,:] + bias[o] (+res[n,o]) )
__global__ __launch_bounds__(256) void k_sgemm(
    const float* __restrict__ W, const float* __restrict__ X,
    const float* __restrict__ bias, const float* __restrict__ res,
    float* __restrict__ out, int K, int OUT, int Ls, int ofs, int do_relu)
{
    __shared__ float sW[16][17];   // [c][o]
    __shared__ float sX[16][17];   // [n][c]
    int o0 = blockIdx.x*16, n0 = blockIdx.y*16;
    int tx = threadIdx.x, ty = threadIdx.y;
    int tid = ty*16 + tx;
    int cl = tid % 16, rl = tid / 16;
    float acc = 0.f;
    for (int kc = 0; kc < K; kc += 16) {
        sW[cl][rl] = W[(size_t)(o0 + rl)*K + kc + cl];
        sX[rl][cl] = (n0 + rl < NN) ? X[(size_t)(n0 + rl)*K + kc + cl] : 0.f;
        __syncthreads();
        #pragma unroll
        for (int kk = 0; kk < 16; kk++) acc += sW[kk][tx] * sX[ty][kk];
        __syncthreads();
    }
    int o = o0 + tx, n = n0 + ty;
    if (n < NN) {
        float val = acc + bias[o];
        if (res) val += res[(size_t)n*OUT + o];
        if (do_relu) val = fmaxf(val, 0.f);
        out[((size_t)n*OUT + o)*Ls + ofs] = val;
    }
}

// ---------------------------------------------------------------------------
// tj attention: window-3 (zero-padded) + embs-token + relay-token, softmax(5)
// out[n,c,t] = xln[n,c,t] + att.  NOTE: q and out may alias (in-place): each
// thread reads ONLY its own t-column of q (into regs, before any store) and
// writes ONLY its own t-column of out — no cross-thread overlap, so no
// __restrict__ on q/out.
__global__ __launch_bounds__(128) void k_attn_tj(
    const float* q, const float* __restrict__ kb, const float* __restrict__ vb,
    const float* __restrict__ ek, const float* __restrict__ ev,
    const float* __restrict__ rk, const float* __restrict__ rv,
    const float* __restrict__ xln, float* out)
{
    int t = threadIdx.x, h = blockIdx.x, n = blockIdx.y;
    size_t base = ((size_t)n*CC + h*DKK)*TT;
    int rbase = n*CC + h*DKK;
    float qv[DKK];
    #pragma unroll
    for (int d = 0; d < DKK; d++) qv[d] = q[base + (size_t)d*TT + t];
    float s0 = 0.f, s1 = 0.f, s2 = 0.f, s3 = 0.f, s4 = 0.f;
    #pragma unroll
    for (int d = 0; d < DKK; d++) {
        s1 += qv[d]*kb[base + (size_t)d*TT + t];
        s3 += qv[d]*ek[base + (size_t)d*TT + t];
        s4 += qv[d]*rk[rbase + d];
    }
    if (t > 0) {
        #pragma unroll
        for (int d = 0; d < DKK; d++) s0 += qv[d]*kb[base + (size_t)d*TT + t - 1];
    }
    if (t < TT-1) {
        #pragma unroll
        for (int d = 0; d < DKK; d++) s2 += qv[d]*kb[base + (size_t)d*TT + t + 1];
    }
    s0 *= SCALE_F; s1 *= SCALE_F; s2 *= SCALE_F; s3 *= SCALE_F; s4 *= SCALE_F;
    float mx = fmaxf(fmaxf(fmaxf(s0, s1), fmaxf(s2, s3)), s4);
    float e0 = expf(s0-mx), e1 = expf(s1-mx), e2 = expf(s2-mx), e3 = expf(s3-mx), e4 = expf(s4-mx);
    float inv = 1.f/(e0+e1+e2+e3+e4);
    e0 *= inv; e1 *= inv; e2 *= inv; e3 *= inv; e4 *= inv;
    // gather neighbor v BEFORE overwriting anything? v is a different buffer
    // than q/out, and out writes touch only this thread's column — safe.
    #pragma unroll
    for (int d = 0; d < DKK; d++) {
        float av = e1*vb[base + (size_t)d*TT + t] + e3*ev[base + (size_t)d*TT + t] + e4*rv[rbase + d];
        if (t > 0)    av += e0*vb[base + (size_t)d*TT + t - 1];
        if (t < TT-1) av += e2*vb[base + (size_t)d*TT + t + 1];
        out[base + (size_t)d*TT + t] = xln[base + (size_t)d*TT + t] + av;
    }
}

// ---------------------------------------------------------------------------
// BatchNorm over (n,t) per channel c; optional leaky_relu on output
__global__ __launch_bounds__(256) void k_bn(const float* __restrict__ x, float* __restrict__ out,
    const float* __restrict__ g, const float* __restrict__ b, int leaky)
{
    int c = blockIdx.x, tid = threadIdx.x;
    const int M = NN*TT;
    float s = 0.f, ss = 0.f;
    for (int i = tid; i < M; i += 256) {
        int n = i / TT, t = i % TT;
        float v = x[((size_t)n*CC + c)*TT + t];
        s += v; ss += v*v;
    }
    for (int off = 32; off; off >>= 1) { s += __shfl_down(s, off); ss += __shfl_down(ss, off); }
    __shared__ float red[2][4];
    int wid = tid >> 6, lid = tid & 63;
    if (lid == 0) { red[0][wid] = s; red[1][wid] = ss; }
    __syncthreads();
    if (tid == 0) {
        float S = 0.f, SS = 0.f;
        for (int w = 0; w < 4; w++) { S += red[0][w]; SS += red[1][w]; }
        float m = S / M;
        float var = SS / M - m*m; if (var < 0.f) var = 0.f;
        red[0][0] = m; red[1][0] = rsqrtf(var + EPS_BN);
    }
    __syncthreads();
    float m = red[0][0], rs = red[1][0];
    float gg = g[c]*rs, bb = b[c];
    for (int i = tid; i < M; i += 256) {
        int n = i / TT, t = i % TT;
        size_t idx = ((size_t)n*CC + c)*TT + t;
        float v = (x[idx] - m)*gg + bb;
        if (leaky) v = v > 0.f ? v : SLOPE*v;
        out[idx] = v;
    }
}

// BatchNorm over n only (relay path), x/out [N,C]
__global__ __launch_bounds__(64) void k_bn_relay(const float* __restrict__ x, float* __restrict__ out,
    const float* __restrict__ g, const float* __restrict__ b, int leaky)
{
    int c = blockIdx.x, tid = threadIdx.x;
    float s = 0.f, ss = 0.f;
    for (int n = tid; n < NN; n += 64) { float v = x[(size_t)n*CC + c]; s += v; ss += v*v; }
    for (int off = 32; off; off >>= 1) { s += __shfl_down(s, off); ss += __shfl_down(ss, off); }
    float S = __shfl(s, 0), SS = __shfl(ss, 0);
    float m = S / NN;
    float var = SS / NN - m*m; if (var < 0.f) var = 0.f;
    float rs = rsqrtf(var + EPS_BN);
    float gg = g[c]*rs, bb = b[c];
    for (int n = tid; n < NN; n += 64) {
        float v = (x[(size_t)n*CC + c] - m)*gg + bb;
        if (leaky) v = v > 0.f ? v : SLOPE*v;
        out[(size_t)n*CC + c] = v;
    }
}

// ---------------------------------------------------------------------------
// relay cross-attention over L1=129 keys; out[n,c] = relay[n,c] + att
__global__ __launch_bounds__(64) void k_attn_tr(
    const float* __restrict__ rq, const float* __restrict__ yk, const float* __restrict__ yv,
    const float* __restrict__ relay, float* __restrict__ out)
{
    int h = blockIdx.x, n = blockIdx.y, tid = threadIdx.x;
    __shared__ float sc[LL1];
    size_t base = ((size_t)n*CC + h*DKK)*LL1;
    const float* qp = rq + (size_t)n*CC + h*DKK;
    float q0[DKK];
    #pragma unroll
    for (int d = 0; d < DKK; d++) q0[d] = qp[d];
    for (int l = tid; l < LL1; l += 64) {
        float s = 0.f;
        #pragma unroll
        for (int d = 0; d < DKK; d++) s += q0[d]*yk[base + (size_t)d*LL1 + l];
        sc[l] = s * SCALE_F;
    }
    __syncthreads();
    float mx = -1e30f;
    for (int l = tid; l < LL1; l += 64) mx = fmaxf(mx, sc[l]);
    for (int off = 32; off; off >>= 1) mx = fmaxf(mx, __shfl_xor(mx, off));
    float sum = 0.f;
    for (int l = tid; l < LL1; l += 64) { float e = expf(sc[l]-mx); sc[l] = e; sum += e; }
    for (int off = 32; off; off >>= 1) sum += __shfl_xor(sum, off);
    __syncthreads();
    if (tid < DKK) {
        int d = tid;
        float acc = 0.f;
        for (int l = 0; l < LL1; l++) acc += sc[l]*yv[base + (size_t)d*LL1 + l];
        acc /= sum;
        out[(size_t)n*CC + h*DKK + d] = relay[(size_t)n*CC + h*DKK + d] + acc;
    }
}

// ---------------------------------------------------------------------------
extern "C" void kernel_launch(void* const* d_in, const int* in_sizes, int n_in,
                              void* d_out, int out_size, void* d_ws, size_t ws_size,
                              hipStream_t stream)
{
    const float* data    = (const float*)d_in[0];
    const float* ln_g    = (const float*)d_in[1];
    const float* ln_b    = (const float*)d_in[2];
    const float* tj_wq   = (const float*)d_in[3];
    const float* tj_bq   = (const float*)d_in[4];
    const float* tj_wk   = (const float*)d_in[5];
    const float* tj_bk   = (const float*)d_in[6];
    const float* tj_wv   = (const float*)d_in[7];
    const float* tj_bv   = (const float*)d_in[8];
    const float* tj_bn_g = (const float*)d_in[9];
    const float* tj_bn_b = (const float*)d_in[10];
    const float* tj_w1   = (const float*)d_in[11];
    const float* tj_b1   = (const float*)d_in[12];
    const float* tj_w2   = (const float*)d_in[13];
    const float* tj_b2   = (const float*)d_in[14];
    const float* tj_fbn_g= (const float*)d_in[15];
    const float* tj_fbn_b= (const float*)d_in[16];
    const float* tr_wq   = (const float*)d_in[17];
    const float* tr_bq   = (const float*)d_in[18];
    const float* tr_wk   = (const float*)d_in[19];
    const float* tr_bk   = (const float*)d_in[20];
    const float* tr_wv   = (const float*)d_in[21];
    const float* tr_bv   = (const float*)d_in[22];
    const float* tr_bn_g = (const float*)d_in[23];
    const float* tr_bn_b = (const float*)d_in[24];
    const float* tr_w1   = (const float*)d_in[25];
    const float* tr_b1   = (const float*)d_in[26];
    const float* tr_w2   = (const float*)d_in[27];
    const float* tr_b2   = (const float*)d_in[28];
    const float* tr_fbn_g= (const float*)d_in[29];
    const float* tr_fbn_b= (const float*)d_in[30];

    const size_t SZ_NCT = (size_t)NN*CC*TT;    // 6,553,600 floats
    const size_t SZ_NC  = (size_t)NN*CC;       // 51,200
    const size_t SZ_Y   = (size_t)NN*CC*LL1;   // 6,604,800

    // Workspace budget: 7*SZ_NCT + smalls = ~186 MB (R1 crashed with 344 MB —
    // suspected ws overflow). d_out doubles as the xln/s2 scratch buffer.
    float* ws = (float*)d_ws;
    size_t off = 0;
    auto alloc = [&](size_t nf) { float* p = ws + off; off += nf; return p; };
    float* embs  = alloc(SZ_NCT);
    float* nodes = alloc(SZ_NCT);
    float* qb    = alloc(SZ_NCT);   // also: attention-out (in-place), then h/yk/yv region
    float* kb    = alloc(SZ_NCT);
    float* vb    = alloc(SZ_NCT);
    float* ekb   = alloc(SZ_NCT);
    float* evb   = alloc(SZ_NCT);   // also: FFN2 output
    float* relayA= alloc(SZ_NC);
    float* relayB= alloc(SZ_NC);
    float* rk    = alloc(SZ_NC);
    float* rv    = alloc(SZ_NC);
    float* rq_   = alloc(SZ_NC);
    float* ret0  = alloc(SZ_NC);
    float* rret  = alloc(SZ_NC);
    float* ro    = alloc(SZ_NC);
    float* rh    = alloc((size_t)NN*DFFF);
    float* h     = qb;              // [N,DFF,T] spans qb..ekb = 4*SZ_NCT exactly
    float* yk    = qb;              // [N,C,L1]
    float* yv    = qb + SZ_Y;       // 2*SZ_Y = 13.2M < 26.2M (qb..ekb) OK
    float* xln   = (float*)d_out;   // LN output / s2 (BN output) scratch
    (void)ws_size; (void)in_sizes; (void)n_in; (void)out_size;

    k_embed<<<dim3(CC, NN), 128, 0, stream>>>(data, embs, nodes, relayA);

    float* relay = relayA;
    float* relay_next = relayB;

    for (int i = 0; i < ITER; i++) {
        const size_t wo = (size_t)i*CC*CC;
        const size_t w1o = (size_t)i*DFFF*CC;

        // nodes -> xln (d_out); old nodes dead afterwards
        k_layernorm<<<(NN*TT)/256, 256, 0, stream>>>(nodes, xln, ln_g + i*CC, ln_b + i*CC);

        dim3 gq((TT+63)/64, CC/64, NN);
        k_gemm<<<gq, 256, 0, stream>>>(tj_wq+wo, xln,  tj_bq+i*CC, nullptr, qb,  CC, CC, TT, TT, 0, 0);
        k_gemm<<<gq, 256, 0, stream>>>(tj_wk+wo, xln,  tj_bk+i*CC, nullptr, kb,  CC, CC, TT, TT, 0, 0);
        k_gemm<<<gq, 256, 0, stream>>>(tj_wv+wo, xln,  tj_bv+i*CC, nullptr, vb,  CC, CC, TT, TT, 0, 0);
        k_gemm<<<gq, 256, 0, stream>>>(tj_wk+wo, embs, tj_bk+i*CC, nullptr, ekb, CC, CC, TT, TT, 0, 0);
        k_gemm<<<gq, 256, 0, stream>>>(tj_wv+wo, embs, tj_bv+i*CC, nullptr, evb, CC, CC, TT, TT, 0, 0);

        dim3 sg(CC/16, (NN+15)/16), sb(16, 16);
        k_sgemm<<<sg, sb, 0, stream>>>(tj_wk+wo, relay, tj_bk+i*CC, nullptr, rk, CC, CC, 1, 0, 0);
        k_sgemm<<<sg, sb, 0, stream>>>(tj_wv+wo, relay, tj_bv+i*CC, nullptr, rv, CC, CC, 1, 0, 0);

        // attention out in-place into qb (per-thread column, safe)
        k_attn_tj<<<dim3(NHH, NN), 128, 0, stream>>>(qb, kb, vb, ekb, evb, rk, rv, xln, qb);
        // BN: qb -> xln(d_out) == s2
        k_bn<<<CC, 256, 0, stream>>>(qb, xln, tj_bn_g+i*CC, tj_bn_b+i*CC, 0);

        // FFN: h = relu(W1*s2+b1) in qb..ekb; out = W2*h+b2+s2 -> evb
        k_gemm<<<dim3((TT+63)/64, DFFF/64, NN), 256, 0, stream>>>(
            tj_w1+w1o, xln, tj_b1+i*DFFF, nullptr, h, CC, DFFF, TT, TT, 0, 1);
        k_gemm<<<dim3((TT+63)/64, CC/64, NN), 256, 0, stream>>>(
            tj_w2+w1o, h, tj_b2+i*CC, xln, evb, DFFF, CC, TT, TT, 0, 0);

        float* nodes_out = (i == ITER-1) ? (float*)d_out : nodes;
        k_bn<<<CC, 256, 0, stream>>>(evb, nodes_out, tj_fbn_g+i*CC, tj_fbn_b+i*CC, 1);

        if (i == ITER-1) break;   // last relay update is dead code

        // yk/yv built directly (no y materialization): cols 1..T from nodes,
        // col 0 from relay via strided sgemm. qb region free here.
        dim3 gy((TT+63)/64, CC/64, NN);
        k_gemm<<<gy, 256, 0, stream>>>(tr_wk+wo, nodes, tr_bk+i*CC, nullptr, yk, CC, CC, TT, LL1, 1, 0);
        k_gemm<<<gy, 256, 0, stream>>>(tr_wv+wo, nodes, tr_bv+i*CC, nullptr, yv, CC, CC, TT, LL1, 1, 0);
        k_sgemm<<<sg, sb, 0, stream>>>(tr_wk+wo, relay, tr_bk+i*CC, nullptr, yk, CC, CC, LL1, 0, 0);
        k_sgemm<<<sg, sb, 0, stream>>>(tr_wv+wo, relay, tr_bv+i*CC, nullptr, yv, CC, CC, LL1, 0, 0);
        k_sgemm<<<sg, sb, 0, stream>>>(tr_wq+wo, relay, tr_bq+i*CC, nullptr, rq_, CC, CC, 1, 0, 0);

        k_attn_tr<<<dim3(NHH, NN), 64, 0, stream>>>(rq_, yk, yv, relay, ret0);
        k_bn_relay<<<CC, 64, 0, stream>>>(ret0, rret, tr_bn_g+i*CC, tr_bn_b+i*CC, 0);

        k_sgemm<<<dim3(DFFF/16, (NN+15)/16), sb, 0, stream>>>(
            tr_w1+w1o, rret, tr_b1+i*DFFF, nullptr, rh, CC, DFFF, 1, 0, 1);
        k_sgemm<<<dim3(CC/16, (NN+15)/16), sb, 0, stream>>>(
            tr_w2+w1o, rh, tr_b2+i*CC, rret, ro, DFFF, CC, 1, 0, 0);
        k_bn_relay<<<CC, 64, 0, stream>>>(ro, relay_next, tr_fbn_g+i*CC, tr_fbn_b+i*CC, 1);

        float* tmp = relay; relay = relay_next; relay_next = tmp;
    }
}

// Round 3
// 2237.168 us; speedup vs baseline: 1.9579x; 1.9579x over previous
//
#include <hip/hip_runtime.h>
#include <cstddef>

#define BB   8
#define VV   25
#define TT   128
#define CC   256
#define NHH  8
#define DKK  32
#define DFFF 1024
#define ITER 4
#define NN   (BB*VV)     // 200
#define NT   (NN*TT)     // 25600
#define LL1  (TT+1)      // 129
#define EPS_LN 1e-6f
#define EPS_BN 1e-5f
#define SLOPE  0.01f
#define SCALE_F 0.17677669529663687f   // 1/sqrt(32)

typedef unsigned short ushort_t;
typedef __attribute__((ext_vector_type(8))) short short8;
typedef __attribute__((ext_vector_type(4))) float floatx4;

__device__ __forceinline__ float bf2f(ushort_t u) {
    union { unsigned int i; float f; } x; x.i = ((unsigned int)u) << 16; return x.f;
}
__device__ __forceinline__ ushort_t f2bf(float f) {
    union { float f; unsigned int i; } x; x.f = f;
    unsigned int r = x.i + 0x7FFFu + ((x.i >> 16) & 1u);   // RNE
    return (ushort_t)(r >> 16);
}

// ---------------------------------------------------------------------------
__global__ __launch_bounds__(256) void k_cast(const float* __restrict__ src,
    ushort_t* __restrict__ dst, int n)
{
    int i = blockIdx.x*256 + threadIdx.x;
    if (i < n) dst[i] = f2bf(src[i]);
}

// ---------------------------------------------------------------------------
// embed: nodes[c,nt]=data[b,c,v,t] f32; embs_bf[c,nt] bf16; relay[n,c]=mean_t
__global__ __launch_bounds__(128) void k_embed(const float* __restrict__ data,
    float* __restrict__ nodes, ushort_t* __restrict__ embs_bf, float* __restrict__ relay)
{
    int c = blockIdx.x, n = blockIdx.y, t = threadIdx.x;
    int b = n / VV, v = n % VV;
    float val = data[(((size_t)b*CC + c)*VV + v)*TT + t];
    size_t o = (size_t)c*NT + n*TT + t;
    nodes[o] = val; embs_bf[o] = f2bf(val);
    float s = val;
    for (int off = 32; off; off >>= 1) s += __shfl_down(s, off);
    __shared__ float red[2];
    if ((t & 63) == 0) red[t >> 6] = s;
    __syncthreads();
    if (t == 0) relay[n*CC + c] = (red[0] + red[1]) * (1.0f / TT);
}

// ---------------------------------------------------------------------------
// LayerNorm over C per column nt; emits f32 + bf16 copies (same [C,NT] layout)
__global__ __launch_bounds__(256) void k_layernorm(const float* __restrict__ x,
    float* __restrict__ outf, ushort_t* __restrict__ outb,
    const float* __restrict__ g, const float* __restrict__ b)
{
    int nt = blockIdx.x*256 + threadIdx.x;   // NT/256 = 100 blocks, exact
    const float* xp = x + nt;
    float s = 0.f, ss = 0.f;
    for (int c = 0; c < CC; c++) { float v = xp[(size_t)c*NT]; s += v; ss += v*v; }
    float m = s * (1.0f/CC);
    float var = ss * (1.0f/CC) - m*m; if (var < 0.f) var = 0.f;
    float rs = rsqrtf(var + EPS_LN);
    for (int c = 0; c < CC; c++) {
        float val = (xp[(size_t)c*NT] - m)*rs*g[c] + b[c];
        outf[(size_t)c*NT + nt] = val;
        outb[(size_t)c*NT + nt] = f2bf(val);
    }
}

// ---------------------------------------------------------------------------
// bf16 MFMA GEMM: out[o, nt] = act( sum_k W[o,k]*X[k,nt] + bias[o] (+res) )
// W bf16 [M,K] row-major, X bf16 [K,NT]. Block tile 128x128, BK=32.
// flags: 1=relu, 2=bf16 out, 4=add f32 res.
#define FL_RELU 1
#define FL_BF16 2
#define FL_RES  4
__global__ __launch_bounds__(256) void k_gemm_mfma(
    const ushort_t* __restrict__ W, const ushort_t* __restrict__ X,
    const float* __restrict__ bias, const float* __restrict__ res,
    float* __restrict__ outf, ushort_t* __restrict__ outb, int K, int flags)
{
    __shared__ ushort_t sA[128*48];   // [m][k] stride 48 (96B: 4-way cap on b128)
    __shared__ ushort_t sB[128*48];   // [n][k] stride 48 (transposed in staging)
    const int n0 = blockIdx.x * 128;
    const int o0 = blockIdx.y * 128;
    const int tid = threadIdx.x;
    const int lane = tid & 63;
    const int wave = tid >> 6;
    const int wm = (wave & 1) * 64;   // wave tile origin (m)
    const int wn = (wave >> 1) * 64;  // wave tile origin (n)
    const int fr = lane >> 4;         // k-group / output row-group
    const int fc = lane & 15;         // m/n row within 16-tile

    floatx4 acc[4][4];
    #pragma unroll
    for (int i = 0; i < 4; i++)
        #pragma unroll
        for (int j = 0; j < 4; j++) acc[i][j] = (floatx4){0.f,0.f,0.f,0.f};

    for (int kc = 0; kc < K; kc += 32) {
        // stage A: 128 rows x 4 chunks of 8; direct vectorized copy
        #pragma unroll
        for (int it = 0; it < 2; it++) {
            int task = tid + it*256;
            int row = task >> 2, ch = task & 3;
            short8 w8 = *(const short8*)&W[(size_t)(o0 + row)*K + kc + ch*8];
            *(short8*)&sA[row*48 + ch*8] = w8;
        }
        // stage B transposed: thread gathers 8 k-contiguous elems for one n
        // (scalar global ushort loads are lane-contiguous in n => coalesced)
        #pragma unroll
        for (int it = 0; it < 2; it++) {
            int task = tid + it*256;
            int n_l = task & 127, ch = task >> 7;
            const ushort_t* xp = &X[(size_t)(kc + ch*8)*NT + n0 + n_l];
            ushort_t tmp[8];
            #pragma unroll
            for (int j = 0; j < 8; j++) tmp[j] = xp[(size_t)j*NT];
            *(short8*)&sB[n_l*48 + ch*8] = *(const short8*)tmp;
        }
        __syncthreads();
        short8 af[4], bf[4];
        #pragma unroll
        for (int mi = 0; mi < 4; mi++)
            af[mi] = *(const short8*)&sA[(wm + mi*16 + fc)*48 + fr*8];
        #pragma unroll
        for (int ni = 0; ni < 4; ni++)
            bf[ni] = *(const short8*)&sB[(wn + ni*16 + fc)*48 + fr*8];
        #pragma unroll
        for (int mi = 0; mi < 4; mi++)
            #pragma unroll
            for (int ni = 0; ni < 4; ni++)
                acc[mi][ni] = __builtin_amdgcn_mfma_f32_16x16x32_bf16(
                    af[mi], bf[ni], acc[mi][ni], 0, 0, 0);
        __syncthreads();
    }
    // epilogue: D[row=(lane>>4)*4+r][col=lane&15] per 16x16 tile (m89 layout)
    #pragma unroll
    for (int mi = 0; mi < 4; mi++) {
        #pragma unroll
        for (int ni = 0; ni < 4; ni++) {
            int o = o0 + wm + mi*16 + fr*4;
            int nn = n0 + wn + ni*16 + fc;
            #pragma unroll
            for (int r = 0; r < 4; r++) {
                float val = acc[mi][ni][r] + bias[o + r];
                size_t idx = (size_t)(o + r)*NT + nn;
                if (flags & FL_RES)  val += res[idx];
                if (flags & FL_RELU) val = fmaxf(val, 0.f);
                if (flags & FL_BF16) outb[idx] = f2bf(val);
                else                 outf[idx] = val;
            }
        }
    }
}

// ---------------------------------------------------------------------------
// Small fp32 GEMM (relay path): out[n,o] = act( W[o,:]*X[n,:] + b[o] (+res) )
__global__ __launch_bounds__(256) void k_sgemm(
    const float* __restrict__ W, const float* __restrict__ X,
    const float* __restrict__ bias, const float* __restrict__ res,
    float* __restrict__ out, int K, int OUT, int do_relu)
{
    __shared__ float sW[16][17];
    __shared__ float sX[16][17];
    int o0 = blockIdx.x*16, n0 = blockIdx.y*16;
    int tx = threadIdx.x, ty = threadIdx.y;
    int tid = ty*16 + tx;
    int cl = tid % 16, rl = tid / 16;
    float acc = 0.f;
    for (int kc = 0; kc < K; kc += 16) {
        sW[cl][rl] = W[(size_t)(o0 + rl)*K + kc + cl];
        sX[rl][cl] = (n0 + rl < NN) ? X[(size_t)(n0 + rl)*K + kc + cl] : 0.f;
        __syncthreads();
        #pragma unroll
        for (int kk = 0; kk < 16; kk++) acc += sW[kk][tx] * sX[ty][kk];
        __syncthreads();
    }
    int o = o0 + tx, n = n0 + ty;
    if (n < NN) {
        float val = acc + bias[o];
        if (res) val += res[(size_t)n*OUT + o];
        if (do_relu) val = fmaxf(val, 0.f);
        out[(size_t)n*OUT + o] = val;
    }
}

// ---------------------------------------------------------------------------
// tj attention, [C,NT] layout, bf16 q/k/v/ek/ev, fp32 rk/rv/xln.
// out[c,nt] = xln[c,nt] + att   (out != q here; both [C,NT])
__global__ __launch_bounds__(128) void k_attn_tj(
    const ushort_t* __restrict__ q, const ushort_t* __restrict__ kb,
    const ushort_t* __restrict__ vb, const ushort_t* __restrict__ ek,
    const ushort_t* __restrict__ ev, const float* __restrict__ rk,
    const float* __restrict__ rv, const float* __restrict__ xln,
    float* __restrict__ out)
{
    int t = threadIdx.x, h = blockIdx.x, n = blockIdx.y;
    size_t base = (size_t)(h*DKK)*NT + n*TT + t;    // + d*NT
    int rbase = n*CC + h*DKK;
    float qv[DKK];
    #pragma unroll
    for (int d = 0; d < DKK; d++) qv[d] = bf2f(q[base + (size_t)d*NT]);
    float s0 = 0.f, s1 = 0.f, s2 = 0.f, s3 = 0.f, s4 = 0.f;
    #pragma unroll
    for (int d = 0; d < DKK; d++) {
        s1 += qv[d]*bf2f(kb[base + (size_t)d*NT]);
        s3 += qv[d]*bf2f(ek[base + (size_t)d*NT]);
        s4 += qv[d]*rk[rbase + d];
    }
    if (t > 0) {
        #pragma unroll
        for (int d = 0; d < DKK; d++) s0 += qv[d]*bf2f(kb[base + (size_t)d*NT - 1]);
    }
    if (t < TT-1) {
        #pragma unroll
        for (int d = 0; d < DKK; d++) s2 += qv[d]*bf2f(kb[base + (size_t)d*NT + 1]);
    }
    s0 *= SCALE_F; s1 *= SCALE_F; s2 *= SCALE_F; s3 *= SCALE_F; s4 *= SCALE_F;
    float mx = fmaxf(fmaxf(fmaxf(s0, s1), fmaxf(s2, s3)), s4);
    float e0 = expf(s0-mx), e1 = expf(s1-mx), e2 = expf(s2-mx), e3 = expf(s3-mx), e4 = expf(s4-mx);
    float inv = 1.f/(e0+e1+e2+e3+e4);
    e0 *= inv; e1 *= inv; e2 *= inv; e3 *= inv; e4 *= inv;
    #pragma unroll
    for (int d = 0; d < DKK; d++) {
        float av = e1*bf2f(vb[base + (size_t)d*NT]) + e3*bf2f(ev[base + (size_t)d*NT])
                 + e4*rv[rbase + d];
        if (t > 0)    av += e0*bf2f(vb[base + (size_t)d*NT - 1]);
        if (t < TT-1) av += e2*bf2f(vb[base + (size_t)d*NT + 1]);
        out[base + (size_t)d*NT] = xln[base + (size_t)d*NT] + av;
    }
}

// ---------------------------------------------------------------------------
// BatchNorm over NT per channel c ([C,NT] rows: fully contiguous).
// outb (optional) bf16 copy; transpose=1 => write d_out [n][c][t] instead.
__global__ __launch_bounds__(256) void k_bn(const float* __restrict__ x,
    float* __restrict__ outf, ushort_t* __restrict__ outb,
    const float* __restrict__ g, const float* __restrict__ b, int leaky, int transpose)
{
    int c = blockIdx.x, tid = threadIdx.x;
    const float* xp = x + (size_t)c*NT;
    float s = 0.f, ss = 0.f;
    for (int i = tid; i < NT; i += 256) { float v = xp[i]; s += v; ss += v*v; }
    for (int off = 32; off; off >>= 1) { s += __shfl_down(s, off); ss += __shfl_down(ss, off); }
    __shared__ float red[2][4];
    int wid = tid >> 6, lid = tid & 63;
    if (lid == 0) { red[0][wid] = s; red[1][wid] = ss; }
    __syncthreads();
    if (tid == 0) {
        float S = 0.f, SS = 0.f;
        for (int w = 0; w < 4; w++) { S += red[0][w]; SS += red[1][w]; }
        float m = S / NT;
        float var = SS / NT - m*m; if (var < 0.f) var = 0.f;
        red[0][0] = m; red[1][0] = rsqrtf(var + EPS_BN);
    }
    __syncthreads();
    float m = red[0][0], rs = red[1][0];
    float gg = g[c]*rs, bb = b[c];
    for (int i = tid; i < NT; i += 256) {
        float v = (xp[i] - m)*gg + bb;
        if (leaky) v = v > 0.f ? v : SLOPE*v;
        if (transpose) {
            outf[(size_t)((i >> 7)*CC + c)*TT + (i & 127)] = v;   // [n][c][t]
        } else {
            outf[(size_t)c*NT + i] = v;
            if (outb) outb[(size_t)c*NT + i] = f2bf(v);
        }
    }
}

// BatchNorm over n only (relay path), x/out [N,C]
__global__ __launch_bounds__(64) void k_bn_relay(const float* __restrict__ x,
    float* __restrict__ out, const float* __restrict__ g, const float* __restrict__ b, int leaky)
{
    int c = blockIdx.x, tid = threadIdx.x;
    float s = 0.f, ss = 0.f;
    for (int n = tid; n < NN; n += 64) { float v = x[(size_t)n*CC + c]; s += v; ss += v*v; }
    for (int off = 32; off; off >>= 1) { s += __shfl_down(s, off); ss += __shfl_down(ss, off); }
    float S = __shfl(s, 0), SS = __shfl(ss, 0);
    float m = S / NN;
    float var = SS / NN - m*m; if (var < 0.f) var = 0.f;
    float rs = rsqrtf(var + EPS_BN);
    float gg = g[c]*rs, bb = b[c];
    for (int n = tid; n < NN; n += 64) {
        float v = (x[(size_t)n*CC + c] - m)*gg + bb;
        if (leaky) v = v > 0.f ? v : SLOPE*v;
        out[(size_t)n*CC + c] = v;
    }
}

// ---------------------------------------------------------------------------
// relay cross-attention; keys = [relay(l=0), nodes(t=l-1)]; yk/yv f32 [C,NT]
__global__ __launch_bounds__(64) void k_attn_tr(
    const float* __restrict__ rq, const float* __restrict__ yk, const float* __restrict__ yv,
    const float* __restrict__ rkY, const float* __restrict__ rvY,
    const float* __restrict__ relay, float* __restrict__ out)
{
    int h = blockIdx.x, n = blockIdx.y, tid = threadIdx.x;
    __shared__ float sc[LL1];
    const float* qp = rq + (size_t)n*CC + h*DKK;
    float q0[DKK];
    #pragma unroll
    for (int d = 0; d < DKK; d++) q0[d] = qp[d];
    for (int l = tid; l < LL1; l += 64) {
        float s = 0.f;
        if (l == 0) {
            #pragma unroll
            for (int d = 0; d < DKK; d++) s += q0[d]*rkY[(size_t)n*CC + h*DKK + d];
        } else {
            size_t yb = (size_t)(h*DKK)*NT + n*TT + (l-1);
            #pragma unroll
            for (int d = 0; d < DKK; d++) s += q0[d]*yk[yb + (size_t)d*NT];
        }
        sc[l] = s * SCALE_F;
    }
    __syncthreads();
    float mx = -1e30f;
    for (int l = tid; l < LL1; l += 64) mx = fmaxf(mx, sc[l]);
    for (int off = 32; off; off >>= 1) mx = fmaxf(mx, __shfl_xor(mx, off));
    float sum = 0.f;
    for (int l = tid; l < LL1; l += 64) { float e = expf(sc[l]-mx); sc[l] = e; sum += e; }
    for (int off = 32; off; off >>= 1) sum += __shfl_xor(sum, off);
    __syncthreads();
    if (tid < DKK) {
        int d = tid;
        float acc = sc[0]*rvY[(size_t)n*CC + h*DKK + d];
        size_t yb = (size_t)(h*DKK + d)*NT + n*TT;
        for (int l = 1; l < LL1; l++) acc += sc[l]*yv[yb + (l-1)];
        acc /= sum;
        out[(size_t)n*CC + h*DKK + d] = relay[(size_t)n*CC + h*DKK + d] + acc;
    }
}

// ---------------------------------------------------------------------------
extern "C" void kernel_launch(void* const* d_in, const int* in_sizes, int n_in,
                              void* d_out, int out_size, void* d_ws, size_t ws_size,
                              hipStream_t stream)
{
    const float* data    = (const float*)d_in[0];
    const float* ln_g    = (const float*)d_in[1];
    const float* ln_b    = (const float*)d_in[2];
    const float* tj_wq   = (const float*)d_in[3];
    const float* tj_bq   = (const float*)d_in[4];
    const float* tj_wk   = (const float*)d_in[5];
    const float* tj_bk   = (const float*)d_in[6];
    const float* tj_wv   = (const float*)d_in[7];
    const float* tj_bv   = (const float*)d_in[8];
    const float* tj_bn_g = (const float*)d_in[9];
    const float* tj_bn_b = (const float*)d_in[10];
    const float* tj_w1   = (const float*)d_in[11];
    const float* tj_b1   = (const float*)d_in[12];
    const float* tj_w2   = (const float*)d_in[13];
    const float* tj_b2   = (const float*)d_in[14];
    const float* tj_fbn_g= (const float*)d_in[15];
    const float* tj_fbn_b= (const float*)d_in[16];
    const float* tr_wq   = (const float*)d_in[17];
    const float* tr_bq   = (const float*)d_in[18];
    const float* tr_wk   = (const float*)d_in[19];
    const float* tr_bk   = (const float*)d_in[20];
    const float* tr_wv   = (const float*)d_in[21];
    const float* tr_bv   = (const float*)d_in[22];
    const float* tr_bn_g = (const float*)d_in[23];
    const float* tr_bn_b = (const float*)d_in[24];
    const float* tr_w1   = (const float*)d_in[25];
    const float* tr_b1   = (const float*)d_in[26];
    const float* tr_w2   = (const float*)d_in[27];
    const float* tr_b2   = (const float*)d_in[28];
    const float* tr_fbn_g= (const float*)d_in[29];
    const float* tr_fbn_b= (const float*)d_in[30];

    const size_t SZ = (size_t)CC*NT;          // 6,553,600 elems (one [C,NT] plane)
    const size_t SZ_NC = (size_t)NN*CC;

    // Workspace layout (~167 MB total; R2's 186 MB was fine, R1's 344 crashed)
    float* ws = (float*)d_ws;
    size_t off = 0;
    auto alloc = [&](size_t nf) { float* p = ws + off; off += nf; return p; };
    float*    nodes   = alloc(SZ);
    float*    xln     = alloc(SZ);             // also s2 (post-attn BN out)
    float*    P2f     = alloc(SZ*5/2);         // q/k/v/ek/ev bf16 | h bf16 | yk+yv f32
    ushort_t* xln_bf  = (ushort_t*)alloc(SZ/2);  // also s2_bf
    ushort_t* nodes_bf= (ushort_t*)alloc(SZ/2);
    ushort_t* embs_bf = (ushort_t*)alloc(SZ/2);
    ushort_t* wq_bf   = (ushort_t*)alloc((size_t)ITER*CC*CC/2);
    ushort_t* wk_bf   = (ushort_t*)alloc((size_t)ITER*CC*CC/2);
    ushort_t* wv_bf   = (ushort_t*)alloc((size_t)ITER*CC*CC/2);
    ushort_t* trk_bf  = (ushort_t*)alloc((size_t)ITER*CC*CC/2);
    ushort_t* trv_bf  = (ushort_t*)alloc((size_t)ITER*CC*CC/2);
    ushort_t* w1_bf   = (ushort_t*)alloc((size_t)ITER*DFFF*CC/2);
    ushort_t* w2_bf   = (ushort_t*)alloc((size_t)ITER*DFFF*CC/2);
    float* relayA = alloc(SZ_NC);
    float* relayB = alloc(SZ_NC);
    float* rk     = alloc(SZ_NC);
    float* rv     = alloc(SZ_NC);
    float* rkY    = alloc(SZ_NC);
    float* rvY    = alloc(SZ_NC);
    float* rq_    = alloc(SZ_NC);
    float* ret0   = alloc(SZ_NC);
    float* rret   = alloc(SZ_NC);
    float* ro     = alloc(SZ_NC);
    float* rh     = alloc((size_t)NN*DFFF);
    (void)ws_size; (void)in_sizes; (void)n_in; (void)out_size;

    ushort_t* qb  = (ushort_t*)P2f;
    ushort_t* kb  = qb + SZ;
    ushort_t* vb  = qb + 2*SZ;
    ushort_t* ekb = qb + 3*SZ;
    ushort_t* evb = qb + 4*SZ;
    ushort_t* h   = qb;                 // [DFF,NT] bf16 = 4*SZ ushorts, fits in 5
    float* yk = P2f;                    // f32 [C,NT]
    float* yv = P2f + SZ;

    // weight pre-cast (all layers at once)
    const int WCC = ITER*CC*CC, WFF = ITER*DFFF*CC;
    k_cast<<<(WCC+255)/256, 256, 0, stream>>>(tj_wq, wq_bf, WCC);
    k_cast<<<(WCC+255)/256, 256, 0, stream>>>(tj_wk, wk_bf, WCC);
    k_cast<<<(WCC+255)/256, 256, 0, stream>>>(tj_wv, wv_bf, WCC);
    k_cast<<<(WCC+255)/256, 256, 0, stream>>>(tr_wk, trk_bf, WCC);
    k_cast<<<(WCC+255)/256, 256, 0, stream>>>(tr_wv, trv_bf, WCC);
    k_cast<<<(WFF+255)/256, 256, 0, stream>>>(tj_w1, w1_bf, WFF);
    k_cast<<<(WFF+255)/256, 256, 0, stream>>>(tj_w2, w2_bf, WFF);

    k_embed<<<dim3(CC, NN), 128, 0, stream>>>(data, nodes, embs_bf, relayA);

    float* relay = relayA;
    float* relay_next = relayB;
    const dim3 G2(NT/128, CC/128);      // (200, 2)
    const dim3 G8(NT/128, DFFF/128);    // (200, 8)
    dim3 sg(CC/16, (NN+15)/16), sb(16, 16);

    for (int i = 0; i < ITER; i++) {
        const size_t wo = (size_t)i*CC*CC;
        const size_t w1o = (size_t)i*DFFF*CC;

        k_layernorm<<<NT/256, 256, 0, stream>>>(nodes, xln, xln_bf, ln_g + i*CC, ln_b + i*CC);

        k_gemm_mfma<<<G2, 256, 0, stream>>>(wq_bf+wo, xln_bf, tj_bq+i*CC, nullptr, nullptr, qb,  CC, FL_BF16);
        k_gemm_mfma<<<G2, 256, 0, stream>>>(wk_bf+wo, xln_bf, tj_bk+i*CC, nullptr, nullptr, kb,  CC, FL_BF16);
        k_gemm_mfma<<<G2, 256, 0, stream>>>(wv_bf+wo, xln_bf, tj_bv+i*CC, nullptr, nullptr, vb,  CC, FL_BF16);
        k_gemm_mfma<<<G2, 256, 0, stream>>>(wk_bf+wo, embs_bf, tj_bk+i*CC, nullptr, nullptr, ekb, CC, FL_BF16);
        k_gemm_mfma<<<G2, 256, 0, stream>>>(wv_bf+wo, embs_bf, tj_bv+i*CC, nullptr, nullptr, evb, CC, FL_BF16);

        k_sgemm<<<sg, sb, 0, stream>>>(tj_wk+wo, relay, tj_bk+i*CC, nullptr, rk, CC, CC, 0);
        k_sgemm<<<sg, sb, 0, stream>>>(tj_wv+wo, relay, tj_bv+i*CC, nullptr, rv, CC, CC, 0);

        // s1 = xln + att -> nodes (old nodes dead after LN)
        k_attn_tj<<<dim3(NHH, NN), 128, 0, stream>>>(qb, kb, vb, ekb, evb, rk, rv, xln, nodes);
        // BN1: nodes(s1) -> xln(s2) f32 + xln_bf(s2_bf)
        k_bn<<<CC, 256, 0, stream>>>(nodes, xln, xln_bf, tj_bn_g+i*CC, tj_bn_b+i*CC, 0, 0);

        // FFN1: h = relu(W1*s2+b1) bf16 (overwrites q/k/v/ek, dead)
        k_gemm_mfma<<<G8, 256, 0, stream>>>(w1_bf+w1o, xln_bf, tj_b1+i*DFFF, nullptr, nullptr, h, CC, FL_RELU|FL_BF16);
        // FFN2: nodes = W2*h + b2 + s2
        k_gemm_mfma<<<G2, 256, 0, stream>>>(w2_bf+w1o, h, tj_b2+i*CC, xln, nodes, nullptr, DFFF, FL_RES);

        if (i == ITER-1) {
            // final BN + leaky, transposed write straight to d_out [N,C,T]
            k_bn<<<CC, 256, 0, stream>>>(nodes, (float*)d_out, nullptr, tj_fbn_g+i*CC, tj_fbn_b+i*CC, 1, 1);
            break;
        }
        k_bn<<<CC, 256, 0, stream>>>(nodes, nodes, nodes_bf, tj_fbn_g+i*CC, tj_fbn_b+i*CC, 1, 0);

        // relay path (h dead; yk/yv reuse P2 region as f32)
        k_gemm_mfma<<<G2, 256, 0, stream>>>(trk_bf+wo, nodes_bf, tr_bk+i*CC, nullptr, yk, nullptr, CC, 0);
        k_gemm_mfma<<<G2, 256, 0, stream>>>(trv_bf+wo, nodes_bf, tr_bv+i*CC, nullptr, yv, nullptr, CC, 0);
        k_sgemm<<<sg, sb, 0, stream>>>(tr_wk+wo, relay, tr_bk+i*CC, nullptr, rkY, CC, CC, 0);
        k_sgemm<<<sg, sb, 0, stream>>>(tr_wv+wo, relay, tr_bv+i*CC, nullptr, rvY, CC, CC, 0);
        k_sgemm<<<sg, sb, 0, stream>>>(tr_wq+wo, relay, tr_bq+i*CC, nullptr, rq_, CC, CC, 0);

        k_attn_tr<<<dim3(NHH, NN), 64, 0, stream>>>(rq_, yk, yv, rkY, rvY, relay, ret0);
        k_bn_relay<<<CC, 64, 0, stream>>>(ret0, rret, tr_bn_g+i*CC, tr_bn_b+i*CC, 0);

        k_sgemm<<<dim3(DFFF/16, (NN+15)/16), sb, 0, stream>>>(
            tr_w1+w1o, rret, tr_b1+i*DFFF, nullptr, rh, CC, DFFF, 1);
        k_sgemm<<<dim3(CC/16, (NN+15)/16), sb, 0, stream>>>(
            tr_w2+w1o, rh, tr_b2+i*CC, rret, ro, DFFF, CC, 0);
        k_bn_relay<<<CC, 64, 0, stream>>>(ro, relay_next, tr_fbn_g+i*CC, tr_fbn_b+i*CC, 1);

        float* tmp = relay; relay = relay_next; relay_next = tmp;
    }
}

// Round 4
// 1926.764 us; speedup vs baseline: 2.2733x; 1.1611x over previous
//
#include <hip/hip_runtime.h>
#include <cstddef>

#define BB   8
#define VV   25
#define TT   128
#define CC   256
#define NHH  8
#define DKK  32
#define DFFF 1024
#define ITER 4
#define NN   (BB*VV)     // 200
#define NT   (NN*TT)     // 25600
#define LL1  (TT+1)      // 129
#define EPS_LN 1e-6f
#define EPS_BN 1e-5f
#define SLOPE  0.01f
#define SCALE_F 0.17677669529663687f   // 1/sqrt(32)

typedef unsigned short ushort_t;
typedef __attribute__((ext_vector_type(8))) short short8;
typedef __attribute__((ext_vector_type(4))) short short4_t;
typedef __attribute__((ext_vector_type(4))) float floatx4;

__device__ __forceinline__ float bf2f(ushort_t u) {
    union { unsigned int i; float f; } x; x.i = ((unsigned int)u) << 16; return x.f;
}
__device__ __forceinline__ ushort_t f2bf(float f) {
    union { float f; unsigned int i; } x; x.f = f;
    unsigned int r = x.i + 0x7FFFu + ((x.i >> 16) & 1u);   // RNE
    return (ushort_t)(r >> 16);
}

// ---------------------------------------------------------------------------
// strided cast/copy: dst[(i/per)*dstride + i%per] = src[i]
__global__ __launch_bounds__(256) void k_cast2(const float* __restrict__ src,
    ushort_t* __restrict__ dst, int per, int dstride, int total)
{
    int i = blockIdx.x*256 + threadIdx.x;
    if (i < total) dst[(size_t)(i/per)*dstride + (i%per)] = f2bf(src[i]);
}
__global__ __launch_bounds__(256) void k_copy2(const float* __restrict__ src,
    float* __restrict__ dst, int per, int dstride, int total)
{
    int i = blockIdx.x*256 + threadIdx.x;
    if (i < total) dst[(size_t)(i/per)*dstride + (i%per)] = src[i];
}

// ---------------------------------------------------------------------------
// embed: nodesf[nt][c] f32 TM + embs_bf TM + relay[n][c]=mean_t. LDS transpose.
__global__ __launch_bounds__(128) void k_embed(const float* __restrict__ data,
    float* __restrict__ nodesf, ushort_t* __restrict__ embs_bf, float* __restrict__ relay)
{
    __shared__ float tile[32][TT+1];
    int cc0 = blockIdx.x*32, n = blockIdx.y;
    int b = n / VV, v = n % VV, t = threadIdx.x;
    for (int cl = 0; cl < 32; cl++)
        tile[cl][t] = data[(((size_t)b*CC + cc0 + cl)*VV + v)*TT + t];
    __syncthreads();
    if (t < 32) {
        float s = 0.f;
        for (int tt = 0; tt < TT; tt++) s += tile[t][tt];
        relay[n*CC + cc0 + t] = s * (1.0f/TT);
    }
    #pragma unroll 8
    for (int it = 0; it < 32; it++) {
        int t_l = it*4 + (t >> 5), c_l = t & 31;
        float val = tile[c_l][t_l];
        size_t o = (size_t)(n*TT + t_l)*CC + cc0 + c_l;
        nodesf[o] = val;
        embs_bf[o] = f2bf(val);
    }
}

// ---------------------------------------------------------------------------
// LayerNorm, token-major, IN-PLACE on x (each lane reads only what it writes);
// also emits bf16 TM copy. One wave per token. grid = NT/4, block 256.
__global__ __launch_bounds__(256) void k_layernorm(float* __restrict__ x,
    ushort_t* __restrict__ outb, const float* __restrict__ g, const float* __restrict__ b)
{
    int wave = threadIdx.x >> 6, lane = threadIdx.x & 63;
    size_t base = (size_t)(blockIdx.x*4 + wave)*CC + lane*4;
    float4 v = *(float4*)&x[base];
    float s  = v.x + v.y + v.z + v.w;
    float ss = v.x*v.x + v.y*v.y + v.z*v.z + v.w*v.w;
    #pragma unroll
    for (int o = 32; o; o >>= 1) { s += __shfl_xor(s, o); ss += __shfl_xor(ss, o); }
    float m = s * (1.0f/CC);
    float var = ss * (1.0f/CC) - m*m; if (var < 0.f) var = 0.f;
    float rs = rsqrtf(var + EPS_LN);
    float4 gg = *(const float4*)&g[lane*4];
    float4 bb = *(const float4*)&b[lane*4];
    v.x = (v.x - m)*rs*gg.x + bb.x;
    v.y = (v.y - m)*rs*gg.y + bb.y;
    v.z = (v.z - m)*rs*gg.z + bb.z;
    v.w = (v.w - m)*rs*gg.w + bb.w;
    *(float4*)&x[base] = v;
    ushort_t o4[4] = {f2bf(v.x), f2bf(v.y), f2bf(v.z), f2bf(v.w)};
    *(short4_t*)&outb[base] = *(short4_t*)o4;
}

// ---------------------------------------------------------------------------
// Unified bf16 MFMA GEMM: D[m][n] = act( A[m,:]·B[n,:] + bias (+BN1(res)) )
// A [M',K], B [N',K] row-major bf16 (both k-contiguous => short8 staging).
// out at m*ostride+n. grid (N'/128, M'/128).
#define FL_RELU  1
#define FL_BF16  2
#define FL_RESBN 4
#define FL_BIASN 8
__global__ __launch_bounds__(256) void k_gemm_mfma(
    const ushort_t* __restrict__ A, const ushort_t* __restrict__ B,
    const float* __restrict__ bias,
    const float* __restrict__ rx, const float* __restrict__ ms,
    const float* __restrict__ bng, const float* __restrict__ bnb,
    float* __restrict__ outf, ushort_t* __restrict__ outb,
    int K, int ostride, int flags)
{
    __shared__ ushort_t sA[128*48];
    __shared__ ushort_t sB[128*48];
    const int n0 = blockIdx.x * 128;
    const int m0 = blockIdx.y * 128;
    const int tid = threadIdx.x;
    const int lane = tid & 63, wave = tid >> 6;
    const int wm = (wave & 1) * 64, wn = (wave >> 1) * 64;
    const int fr = lane >> 4, fc = lane & 15;

    floatx4 acc[4][4];
    #pragma unroll
    for (int i = 0; i < 4; i++)
        #pragma unroll
        for (int j = 0; j < 4; j++) acc[i][j] = (floatx4){0.f,0.f,0.f,0.f};

    for (int kc = 0; kc < K; kc += 32) {
        #pragma unroll
        for (int it = 0; it < 2; it++) {
            int task = tid + it*256;
            int row = task >> 2, ch = task & 3;
            *(short8*)&sA[row*48 + ch*8] =
                *(const short8*)&A[(size_t)(m0 + row)*K + kc + ch*8];
            *(short8*)&sB[row*48 + ch*8] =
                *(const short8*)&B[(size_t)(n0 + row)*K + kc + ch*8];
        }
        __syncthreads();
        short8 af[4], bfr[4];
        #pragma unroll
        for (int mi = 0; mi < 4; mi++)
            af[mi] = *(const short8*)&sA[(wm + mi*16 + fc)*48 + fr*8];
        #pragma unroll
        for (int ni = 0; ni < 4; ni++)
            bfr[ni] = *(const short8*)&sB[(wn + ni*16 + fc)*48 + fr*8];
        #pragma unroll
        for (int mi = 0; mi < 4; mi++)
            #pragma unroll
            for (int ni = 0; ni < 4; ni++)
                acc[mi][ni] = __builtin_amdgcn_mfma_f32_16x16x32_bf16(
                    af[mi], bfr[ni], acc[mi][ni], 0, 0, 0);
        __syncthreads();
    }
    #pragma unroll
    for (int mi = 0; mi < 4; mi++) {
        #pragma unroll
        for (int ni = 0; ni < 4; ni++) {
            int n = n0 + wn + ni*16 + fc;
            float bn_ = (flags & FL_BIASN) ? bias[n] : 0.f;
            #pragma unroll
            for (int r = 0; r < 4; r++) {
                int m = m0 + wm + mi*16 + fr*4 + r;
                float val = acc[mi][ni][r] + ((flags & FL_BIASN) ? bn_ : bias[m]);
                size_t idx = (size_t)m*ostride + n;
                if (flags & FL_RESBN)   // res = BN1(s1) recomputed: m is channel
                    val += (rx[idx] - ms[m])*ms[CC + m]*bng[m] + bnb[m];
                if (flags & FL_RELU) val = fmaxf(val, 0.f);
                if (flags & FL_BF16) outb[idx] = f2bf(val);
                else                 outf[idx] = val;
            }
        }
    }
}

// ---------------------------------------------------------------------------
// Small fp32 GEMM (relay path), as R3 (proven)
__global__ __launch_bounds__(256) void k_sgemm(
    const float* __restrict__ W, const float* __restrict__ X,
    const float* __restrict__ bias, const float* __restrict__ res,
    float* __restrict__ out, int K, int OUT, int do_relu)
{
    __shared__ float sW[16][17];
    __shared__ float sX[16][17];
    int o0 = blockIdx.x*16, n0 = blockIdx.y*16;
    int tx = threadIdx.x, ty = threadIdx.y;
    int tid = ty*16 + tx;
    int cl = tid % 16, rl = tid / 16;
    float acc = 0.f;
    for (int kc = 0; kc < K; kc += 16) {
        sW[cl][rl] = W[(size_t)(o0 + rl)*K + kc + cl];
        sX[rl][cl] = (n0 + rl < NN) ? X[(size_t)(n0 + rl)*K + kc + cl] : 0.f;
        __syncthreads();
        #pragma unroll
        for (int kk = 0; kk < 16; kk++) acc += sW[kk][tx] * sX[ty][kk];
        __syncthreads();
    }
    int o = o0 + tx, n = n0 + ty;
    if (n < NN) {
        float val = acc + bias[o];
        if (res) val += res[(size_t)n*OUT + o];
        if (do_relu) val = fmaxf(val, 0.f);
        out[(size_t)n*OUT + o] = val;
    }
}

// ---------------------------------------------------------------------------
// tj attention: q/k/v/ek/ev bf16 MM [c][nt]; rkv f32 [n][512] (k|v);
// xln f32 TM [nt][c]. out = s1 f32 MM.
__global__ __launch_bounds__(128) void k_attn_tj(
    const ushort_t* __restrict__ q, const ushort_t* __restrict__ kb,
    const ushort_t* __restrict__ vb, const ushort_t* __restrict__ ek,
    const ushort_t* __restrict__ ev, const float* __restrict__ rkv,
    const float* __restrict__ xln, float* __restrict__ out)
{
    int t = threadIdx.x, h = blockIdx.x, n = blockIdx.y;
    size_t base = (size_t)(h*DKK)*NT + n*TT + t;
    int rb = n*512 + h*DKK;
    float qv[DKK];
    #pragma unroll
    for (int d = 0; d < DKK; d++) qv[d] = bf2f(q[base + (size_t)d*NT]);
    float s0 = 0.f, s1 = 0.f, s2 = 0.f, s3 = 0.f, s4 = 0.f;
    #pragma unroll
    for (int d = 0; d < DKK; d++) {
        s1 += qv[d]*bf2f(kb[base + (size_t)d*NT]);
        s3 += qv[d]*bf2f(ek[base + (size_t)d*NT]);
        s4 += qv[d]*rkv[rb + d];
    }
    if (t > 0) {
        #pragma unroll
        for (int d = 0; d < DKK; d++) s0 += qv[d]*bf2f(kb[base + (size_t)d*NT - 1]);
    }
    if (t < TT-1) {
        #pragma unroll
        for (int d = 0; d < DKK; d++) s2 += qv[d]*bf2f(kb[base + (size_t)d*NT + 1]);
    }
    s0 *= SCALE_F; s1 *= SCALE_F; s2 *= SCALE_F; s3 *= SCALE_F; s4 *= SCALE_F;
    float mx = fmaxf(fmaxf(fmaxf(s0, s1), fmaxf(s2, s3)), s4);
    float e0 = expf(s0-mx), e1 = expf(s1-mx), e2 = expf(s2-mx), e3 = expf(s3-mx), e4 = expf(s4-mx);
    float inv = 1.f/(e0+e1+e2+e3+e4);
    e0 *= inv; e1 *= inv; e2 *= inv; e3 *= inv; e4 *= inv;
    size_t xb = (size_t)(n*TT + t)*CC + h*DKK;
    #pragma unroll
    for (int d = 0; d < DKK; d++) {
        float av = e1*bf2f(vb[base + (size_t)d*NT]) + e3*bf2f(ev[base + (size_t)d*NT])
                 + e4*rkv[rb + 256 + d];
        if (t > 0)    av += e0*bf2f(vb[base + (size_t)d*NT - 1]);
        if (t < TT-1) av += e2*bf2f(vb[base + (size_t)d*NT + 1]);
        out[base + (size_t)d*NT] = xln[xb + d] + av;
    }
}

// ---------------------------------------------------------------------------
// BN stats: ms[c]=mean, ms[C+c]=rstd. x MM [c][nt] contiguous rows.
__global__ __launch_bounds__(256) void k_bnstats(const float* __restrict__ x,
    float* __restrict__ ms)
{
    int c = blockIdx.x, tid = threadIdx.x;
    const float* xp = x + (size_t)c*NT;
    float s = 0.f, ss = 0.f;
    for (int i = tid*4; i < NT; i += 1024) {
        float4 v = *(const float4*)&xp[i];
        s += v.x + v.y + v.z + v.w;
        ss += v.x*v.x + v.y*v.y + v.z*v.z + v.w*v.w;
    }
    for (int off = 32; off; off >>= 1) { s += __shfl_down(s, off); ss += __shfl_down(ss, off); }
    __shared__ float red[2][4];
    int wid = tid >> 6, lid = tid & 63;
    if (lid == 0) { red[0][wid] = s; red[1][wid] = ss; }
    __syncthreads();
    if (tid == 0) {
        float S = 0.f, SS = 0.f;
        for (int w = 0; w < 4; w++) { S += red[0][w]; SS += red[1][w]; }
        float m = S / NT;
        float var = SS / NT - m*m; if (var < 0.f) var = 0.f;
        ms[c] = m; ms[CC + c] = rsqrtf(var + EPS_BN);
    }
}

// BN apply + LDS transpose: read x MM, write TM f32 (opt) + TM bf16.
// grid (NT/64, C/64), block 256.
__global__ __launch_bounds__(256) void k_bn_apply(const float* __restrict__ x,
    const float* __restrict__ ms, const float* __restrict__ g, const float* __restrict__ b,
    float* __restrict__ outTMf, ushort_t* __restrict__ outTMb, int leaky)
{
    __shared__ float tile[64][65];
    int nt0 = blockIdx.x*64, c0 = blockIdx.y*64;
    int tid = threadIdx.x;
    int lane_nt = tid & 63, wq = tid >> 6;
    #pragma unroll
    for (int it = 0; it < 16; it++) {
        int c_l = it*4 + wq, c = c0 + c_l;
        float v = x[(size_t)c*NT + nt0 + lane_nt];
        v = (v - ms[c])*ms[CC + c]*g[c] + b[c];
        if (leaky) v = v > 0.f ? v : SLOPE*v;
        tile[lane_nt][c_l] = v;
    }
    __syncthreads();
    #pragma unroll
    for (int it = 0; it < 16; it++) {
        int nt_l = it*4 + wq, c_l = tid & 63;
        float v = tile[nt_l][c_l];
        size_t o = (size_t)(nt0 + nt_l)*CC + c0 + c_l;
        if (outTMf) outTMf[o] = v;
        outTMb[o] = f2bf(v);
    }
}

// final BN: apply + leaky, write d_out [n][c][t] directly from MM rows
__global__ __launch_bounds__(256) void k_bn_out(const float* __restrict__ x,
    const float* __restrict__ ms, const float* __restrict__ g, const float* __restrict__ b,
    float* __restrict__ out)
{
    int c = blockIdx.x, tid = threadIdx.x;
    float m = ms[c], gg = g[c]*ms[CC + c], bb = b[c];
    const float* xp = x + (size_t)c*NT;
    for (int i = tid; i < NT; i += 256) {
        float v = (xp[i] - m)*gg + bb;
        v = v > 0.f ? v : SLOPE*v;
        out[(size_t)((i >> 7)*CC + c)*TT + (i & 127)] = v;
    }
}

// BatchNorm over n only (relay path), x/out [N,C]
__global__ __launch_bounds__(64) void k_bn_relay(const float* __restrict__ x,
    float* __restrict__ out, const float* __restrict__ g, const float* __restrict__ b, int leaky)
{
    int c = blockIdx.x, tid = threadIdx.x;
    float s = 0.f, ss = 0.f;
    for (int n = tid; n < NN; n += 64) { float v = x[(size_t)n*CC + c]; s += v; ss += v*v; }
    for (int off = 32; off; off >>= 1) { s += __shfl_down(s, off); ss += __shfl_down(ss, off); }
    float S = __shfl(s, 0), SS = __shfl(ss, 0);
    float m = S / NN;
    float var = SS / NN - m*m; if (var < 0.f) var = 0.f;
    float rs = rsqrtf(var + EPS_BN);
    float gg = g[c]*rs, bb = b[c];
    for (int n = tid; n < NN; n += 64) {
        float v = (x[(size_t)n*CC + c] - m)*gg + bb;
        if (leaky) v = v > 0.f ? v : SLOPE*v;
        out[(size_t)n*CC + c] = v;
    }
}

// ---------------------------------------------------------------------------
// relay cross-attention; yk/yv MM f32; rkvY [n][512] (k|v); l=0 key = rkvY
__global__ __launch_bounds__(64) void k_attn_tr(
    const float* __restrict__ rq, const float* __restrict__ yk, const float* __restrict__ yv,
    const float* __restrict__ rkvY, const float* __restrict__ relay, float* __restrict__ out)
{
    int h = blockIdx.x, n = blockIdx.y, tid = threadIdx.x;
    __shared__ float sc[LL1];
    const float* qp = rq + (size_t)n*CC + h*DKK;
    float q0[DKK];
    #pragma unroll
    for (int d = 0; d < DKK; d++) q0[d] = qp[d];
    for (int l = tid; l < LL1; l += 64) {
        float s = 0.f;
        if (l == 0) {
            #pragma unroll
            for (int d = 0; d < DKK; d++) s += q0[d]*rkvY[n*512 + h*DKK + d];
        } else {
            size_t yb = (size_t)(h*DKK)*NT + n*TT + (l-1);
            #pragma unroll
            for (int d = 0; d < DKK; d++) s += q0[d]*yk[yb + (size_t)d*NT];
        }
        sc[l] = s * SCALE_F;
    }
    __syncthreads();
    float mx = -1e30f;
    for (int l = tid; l < LL1; l += 64) mx = fmaxf(mx, sc[l]);
    for (int off = 32; off; off >>= 1) mx = fmaxf(mx, __shfl_xor(mx, off));
    float sum = 0.f;
    for (int l = tid; l < LL1; l += 64) { float e = expf(sc[l]-mx); sc[l] = e; sum += e; }
    for (int off = 32; off; off >>= 1) sum += __shfl_xor(sum, off);
    __syncthreads();
    if (tid < DKK) {
        int d = tid;
        float acc = sc[0]*rkvY[n*512 + 256 + h*DKK + d];
        size_t yb = (size_t)(h*DKK + d)*NT + n*TT;
        for (int l = 1; l < LL1; l++) acc += sc[l]*yv[yb + (l-1)];
        acc /= sum;
        out[(size_t)n*CC + h*DKK + d] = relay[(size_t)n*CC + h*DKK + d] + acc;
    }
}

// ---------------------------------------------------------------------------
extern "C" void kernel_launch(void* const* d_in, const int* in_sizes, int n_in,
                              void* d_out, int out_size, void* d_ws, size_t ws_size,
                              hipStream_t stream)
{
    const float* data    = (const float*)d_in[0];
    const float* ln_g    = (const float*)d_in[1];
    const float* ln_b    = (const float*)d_in[2];
    const float* tj_wq   = (const float*)d_in[3];
    const float* tj_bq   = (const float*)d_in[4];
    const float* tj_wk   = (const float*)d_in[5];
    const float* tj_bk   = (const float*)d_in[6];
    const float* tj_wv   = (const float*)d_in[7];
    const float* tj_bv   = (const float*)d_in[8];
    const float* tj_bn_g = (const float*)d_in[9];
    const float* tj_bn_b = (const float*)d_in[10];
    const float* tj_w1   = (const float*)d_in[11];
    const float* tj_b1   = (const float*)d_in[12];
    const float* tj_w2   = (const float*)d_in[13];
    const float* tj_b2   = (const float*)d_in[14];
    const float* tj_fbn_g= (const float*)d_in[15];
    const float* tj_fbn_b= (const float*)d_in[16];
    const float* tr_wq   = (const float*)d_in[17];
    const float* tr_bq   = (const float*)d_in[18];
    const float* tr_wk   = (const float*)d_in[19];
    const float* tr_bk   = (const float*)d_in[20];
    const float* tr_wv   = (const float*)d_in[21];
    const float* tr_bv   = (const float*)d_in[22];
    const float* tr_bn_g = (const float*)d_in[23];
    const float* tr_bn_b = (const float*)d_in[24];
    const float* tr_w1   = (const float*)d_in[25];
    const float* tr_b1   = (const float*)d_in[26];
    const float* tr_w2   = (const float*)d_in[27];
    const float* tr_b2   = (const float*)d_in[28];
    const float* tr_fbn_g= (const float*)d_in[29];
    const float* tr_fbn_b= (const float*)d_in[30];

    const size_t SZ = (size_t)CC*NT;     // 6,553,600
    const size_t SZ_NC = (size_t)NN*CC;  // 51,200

    // ws budget ~171 MB (R3's ~167 passed)
    float* ws = (float*)d_ws;
    size_t off = 0;
    auto alloc = [&](size_t nf) { float* p = ws + off; off += nf; return p; };
    float*    nodesf  = alloc(SZ);        // TM f32; LN runs in-place here
    float*    sbuf    = alloc(SZ);        // MM f32: s1 / s1b (FFN2 in-place)
    float*    P1      = alloc(SZ*5/2);    // qkv+ekv bf16 MM | h bf16 TM | ykv f32 MM
    ushort_t* xs_bf   = (ushort_t*)alloc(SZ/2);  // xln_bf then s2_bf (TM)
    ushort_t* embs_bf = (ushort_t*)alloc(SZ/2);  // TM, persists
    ushort_t* nodes_bf= (ushort_t*)alloc(SZ/2);  // TM, per-layer
    float* msA    = alloc(2*CC);
    float* msB    = alloc(2*CC);
    float* relayA = alloc(SZ_NC);
    float* relayB = alloc(SZ_NC);
    float* rkv    = alloc(2*SZ_NC);
    float* rkvY   = alloc(2*SZ_NC);
    float* rq_    = alloc(SZ_NC);
    float* ret0   = alloc(SZ_NC);
    float* rret   = alloc(SZ_NC);
    float* ro     = alloc(SZ_NC);
    float* rh     = alloc((size_t)NN*DFFF);
    ushort_t* wqkv_bf  = (ushort_t*)alloc((size_t)ITER*768*CC/2);
    ushort_t* wkvtr_bf = (ushort_t*)alloc((size_t)ITER*512*CC/2);
    ushort_t* w1_bf    = (ushort_t*)alloc((size_t)ITER*DFFF*CC/2);
    ushort_t* w2_bf    = (ushort_t*)alloc((size_t)ITER*DFFF*CC/2);
    float* wkvtj_f = alloc((size_t)ITER*512*CC);
    float* wkvtr_f = alloc((size_t)ITER*512*CC);
    float* bqkv    = alloc((size_t)ITER*768);
    float* bkvtr   = alloc((size_t)ITER*512);
    (void)ws_size; (void)in_sizes; (void)n_in; (void)out_size;

    ushort_t* qkv_us = (ushort_t*)P1;            // 3*SZ ushorts (q|k|v MM)
    ushort_t* ekv_us = qkv_us + 3*SZ;            // 2*SZ ushorts (ek|ev MM)
    ushort_t* h_us   = (ushort_t*)P1;            // 4*SZ ushorts (h TM), after attn
    float*    ykv_f  = P1;                       // 2*SZ f32 (yk|yv MM), after FFN2

    // one-time weight/bias concat casts
    const int TCC = ITER*CC*CC, TFF = ITER*DFFF*CC;
    k_cast2<<<(TCC+255)/256, 256, 0, stream>>>(tj_wq, wqkv_bf,          65536, 196608, TCC);
    k_cast2<<<(TCC+255)/256, 256, 0, stream>>>(tj_wk, wqkv_bf +  65536, 65536, 196608, TCC);
    k_cast2<<<(TCC+255)/256, 256, 0, stream>>>(tj_wv, wqkv_bf + 131072, 65536, 196608, TCC);
    k_cast2<<<(TCC+255)/256, 256, 0, stream>>>(tr_wk, wkvtr_bf,         65536, 131072, TCC);
    k_cast2<<<(TCC+255)/256, 256, 0, stream>>>(tr_wv, wkvtr_bf + 65536, 65536, 131072, TCC);
    k_cast2<<<(TFF+255)/256, 256, 0, stream>>>(tj_w1, w1_bf, TFF, TFF, TFF);
    k_cast2<<<(TFF+255)/256, 256, 0, stream>>>(tj_w2, w2_bf, TFF, TFF, TFF);
    k_copy2<<<(ITER*256+255)/256, 256, 0, stream>>>(tj_bq, bqkv,       256, 768, ITER*256);
    k_copy2<<<(ITER*256+255)/256, 256, 0, stream>>>(tj_bk, bqkv + 256, 256, 768, ITER*256);
    k_copy2<<<(ITER*256+255)/256, 256, 0, stream>>>(tj_bv, bqkv + 512, 256, 768, ITER*256);
    k_copy2<<<(ITER*256+255)/256, 256, 0, stream>>>(tr_bk, bkvtr,      256, 512, ITER*256);
    k_copy2<<<(ITER*256+255)/256, 256, 0, stream>>>(tr_bv, bkvtr+256,  256, 512, ITER*256);
    k_copy2<<<(TCC+255)/256, 256, 0, stream>>>(tj_wk, wkvtj_f,         65536, 131072, TCC);
    k_copy2<<<(TCC+255)/256, 256, 0, stream>>>(tj_wv, wkvtj_f + 65536, 65536, 131072, TCC);
    k_copy2<<<(TCC+255)/256, 256, 0, stream>>>(tr_wk, wkvtr_f,         65536, 131072, TCC);
    k_copy2<<<(TCC+255)/256, 256, 0, stream>>>(tr_wv, wkvtr_f + 65536, 65536, 131072, TCC);

    k_embed<<<dim3(8, NN), 128, 0, stream>>>(data, nodesf, embs_bf, relayA);

    float* relay = relayA;
    float* relay_next = relayB;
    dim3 sb16(16, 16);

    for (int i = 0; i < ITER; i++) {
        const size_t wo768 = (size_t)i*768*CC;
        const size_t wo512 = (size_t)i*512*CC;
        const size_t woff  = (size_t)i*DFFF*CC;

        // LN in-place on nodesf (TM) + xln_bf
        k_layernorm<<<NT/4, 256, 0, stream>>>(nodesf, xs_bf, ln_g + i*CC, ln_b + i*CC);

        // fused q|k|v projection: M=768
        k_gemm_mfma<<<dim3(NT/128, 6), 256, 0, stream>>>(
            wqkv_bf + wo768, xs_bf, bqkv + i*768, nullptr, nullptr, nullptr, nullptr,
            nullptr, qkv_us, CC, NT, FL_BF16);
        // embs k|v: rows 256-767 of wqkv, M=512
        k_gemm_mfma<<<dim3(NT/128, 4), 256, 0, stream>>>(
            wqkv_bf + wo768 + 65536, embs_bf, bqkv + i*768 + 256, nullptr, nullptr, nullptr, nullptr,
            nullptr, ekv_us, CC, NT, FL_BF16);
        // relay k|v (f32 small GEMM, OUT=512)
        k_sgemm<<<dim3(32, (NN+15)/16), sb16, 0, stream>>>(
            wkvtj_f + wo512, relay, bqkv + i*768 + 256, nullptr, rkv, CC, 512, 0);

        k_attn_tj<<<dim3(NHH, NN), 128, 0, stream>>>(
            qkv_us, qkv_us + SZ, qkv_us + 2*SZ, ekv_us, ekv_us + SZ, rkv, nodesf, sbuf);

        k_bnstats<<<CC, 256, 0, stream>>>(sbuf, msA);
        // BN1 apply: s2_bf TM only (FFN2 recomputes s2 in epilogue via RESBN)
        k_bn_apply<<<dim3(NT/64, CC/64), 256, 0, stream>>>(
            sbuf, msA, tj_bn_g + i*CC, tj_bn_b + i*CC, nullptr, xs_bf, 0);

        // FFN1: A=s2 TM (m=nt), B=W1 (n=f) -> h TM bf16, col-bias+relu
        k_gemm_mfma<<<dim3(DFFF/128, NT/128), 256, 0, stream>>>(
            xs_bf, w1_bf + woff, tj_b1 + i*DFFF, nullptr, nullptr, nullptr, nullptr,
            nullptr, h_us, CC, DFFF, FL_BIASN | FL_RELU | FL_BF16);
        // FFN2: A=W2 (m=c), B=h TM -> sbuf in-place, + BN1(s1) residual
        k_gemm_mfma<<<dim3(NT/128, 2), 256, 0, stream>>>(
            w2_bf + woff, h_us, tj_b2 + i*CC, sbuf, msA, tj_bn_g + i*CC, tj_bn_b + i*CC,
            sbuf, nullptr, DFFF, NT, FL_RESBN);

        k_bnstats<<<CC, 256, 0, stream>>>(sbuf, msB);
        if (i == ITER-1) {
            k_bn_out<<<CC, 256, 0, stream>>>(sbuf, msB, tj_fbn_g + i*CC, tj_fbn_b + i*CC,
                                             (float*)d_out);
            break;   // last relay update is dead code
        }
        k_bn_apply<<<dim3(NT/64, CC/64), 256, 0, stream>>>(
            sbuf, msB, tj_fbn_g + i*CC, tj_fbn_b + i*CC, nodesf, nodes_bf, 1);

        // relay path: y k|v projection of nodes, M=512, f32 out MM
        k_gemm_mfma<<<dim3(NT/128, 4), 256, 0, stream>>>(
            wkvtr_bf + wo512, nodes_bf, bkvtr + i*512, nullptr, nullptr, nullptr, nullptr,
            ykv_f, nullptr, CC, NT, 0);
        k_sgemm<<<dim3(16, (NN+15)/16), sb16, 0, stream>>>(
            tr_wq + (size_t)i*CC*CC, relay, tr_bq + i*CC, nullptr, rq_, CC, CC, 0);
        k_sgemm<<<dim3(32, (NN+15)/16), sb16, 0, stream>>>(
            wkvtr_f + wo512, relay, bkvtr + i*512, nullptr, rkvY, CC, 512, 0);

        k_attn_tr<<<dim3(NHH, NN), 64, 0, stream>>>(rq_, ykv_f, ykv_f + SZ, rkvY, relay, ret0);
        k_bn_relay<<<CC, 64, 0, stream>>>(ret0, rret, tr_bn_g + i*CC, tr_bn_b + i*CC, 0);

        k_sgemm<<<dim3(DFFF/16, (NN+15)/16), sb16, 0, stream>>>(
            tr_w1 + woff, rret, tr_b1 + i*DFFF, nullptr, rh, CC, DFFF, 1);
        k_sgemm<<<dim3(16, (NN+15)/16), sb16, 0, stream>>>(
            tr_w2 + woff, rh, tr_b2 + i*CC, rret, ro, DFFF, CC, 0);
        k_bn_relay<<<CC, 64, 0, stream>>>(ro, relay_next, tr_fbn_g + i*CC, tr_fbn_b + i*CC, 1);

        float* tmp = relay; relay = relay_next; relay_next = tmp;
    }
}

// Round 5
// 1656.661 us; speedup vs baseline: 2.6440x; 1.1630x over previous
//
#include <hip/hip_runtime.h>
#include <cstddef>

#define BB   8
#define VV   25
#define TT   128
#define CC   256
#define NHH  8
#define DKK  32
#define DFFF 1024
#define ITER 4
#define NN   (BB*VV)     // 200
#define NT   (NN*TT)     // 25600
#define LL1  (TT+1)      // 129
#define EPS_LN 1e-6f
#define EPS_BN 1e-5f
#define SLOPE  0.01f
#define SCALE_F 0.17677669529663687f   // 1/sqrt(32)

typedef unsigned short ushort_t;
typedef __attribute__((ext_vector_type(8))) short short8;
typedef __attribute__((ext_vector_type(4))) short short4_t;
typedef __attribute__((ext_vector_type(4))) float floatx4;

union U8 { short8 v; ushort_t u[8]; };

__device__ __forceinline__ float bf2f(ushort_t u) {
    union { unsigned int i; float f; } x; x.i = ((unsigned int)u) << 16; return x.f;
}
__device__ __forceinline__ ushort_t f2bf(float f) {
    union { float f; unsigned int i; } x; x.f = f;
    unsigned int r = x.i + 0x7FFFu + ((x.i >> 16) & 1u);   // RNE
    return (ushort_t)(r >> 16);
}

// load 32 bf16 (contiguous) -> f32 regs
__device__ __forceinline__ void ld32(const ushort_t* p, float* q) {
    #pragma unroll
    for (int c8 = 0; c8 < 4; c8++) {
        U8 u; u.v = *(const short8*)(p + c8*8);
        #pragma unroll
        for (int j = 0; j < 8; j++) q[c8*8+j] = bf2f(u.u[j]);
    }
}
__device__ __forceinline__ float dot32(const ushort_t* p, const float* q) {
    float s = 0.f;
    #pragma unroll
    for (int c8 = 0; c8 < 4; c8++) {
        U8 u; u.v = *(const short8*)(p + c8*8);
        #pragma unroll
        for (int j = 0; j < 8; j++) s += q[c8*8+j]*bf2f(u.u[j]);
    }
    return s;
}
__device__ __forceinline__ void acc32(const ushort_t* p, float e, float* av) {
    #pragma unroll
    for (int c8 = 0; c8 < 4; c8++) {
        U8 u; u.v = *(const short8*)(p + c8*8);
        #pragma unroll
        for (int j = 0; j < 8; j++) av[c8*8+j] += e*bf2f(u.u[j]);
    }
}

// ---------------------------------------------------------------------------
// strided cast/copy: dst[(i/per)*dstride + i%per] = src[i]
__global__ __launch_bounds__(256) void k_cast2(const float* __restrict__ src,
    ushort_t* __restrict__ dst, int per, int dstride, int total)
{
    int i = blockIdx.x*256 + threadIdx.x;
    if (i < total) dst[(size_t)(i/per)*dstride + (i%per)] = f2bf(src[i]);
}
__global__ __launch_bounds__(256) void k_copy2(const float* __restrict__ src,
    float* __restrict__ dst, int per, int dstride, int total)
{
    int i = blockIdx.x*256 + threadIdx.x;
    if (i < total) dst[(size_t)(i/per)*dstride + (i%per)] = src[i];
}

// ---------------------------------------------------------------------------
// embed: nodesf[nt][c] f32 TM + embs_bf TM + relay[n][c]=mean_t. LDS transpose.
__global__ __launch_bounds__(128) void k_embed(const float* __restrict__ data,
    float* __restrict__ nodesf, ushort_t* __restrict__ embs_bf, float* __restrict__ relay)
{
    __shared__ float tile[32][TT+1];
    int cc0 = blockIdx.x*32, n = blockIdx.y;
    int b = n / VV, v = n % VV, t = threadIdx.x;
    for (int cl = 0; cl < 32; cl++)
        tile[cl][t] = data[(((size_t)b*CC + cc0 + cl)*VV + v)*TT + t];
    __syncthreads();
    if (t < 32) {
        float s = 0.f;
        for (int tt = 0; tt < TT; tt++) s += tile[t][tt];
        relay[n*CC + cc0 + t] = s * (1.0f/TT);
    }
    #pragma unroll 8
    for (int it = 0; it < 32; it++) {
        int t_l = it*4 + (t >> 5), c_l = t & 31;
        float val = tile[c_l][t_l];
        size_t o = (size_t)(n*TT + t_l)*CC + cc0 + c_l;
        nodesf[o] = val;
        embs_bf[o] = f2bf(val);
    }
}

// ---------------------------------------------------------------------------
// LayerNorm TM in-place + bf16 TM copy. One wave per token.
__global__ __launch_bounds__(256) void k_layernorm(float* __restrict__ x,
    ushort_t* __restrict__ outb, const float* __restrict__ g, const float* __restrict__ b)
{
    int wave = threadIdx.x >> 6, lane = threadIdx.x & 63;
    size_t base = (size_t)(blockIdx.x*4 + wave)*CC + lane*4;
    float4 v = *(float4*)&x[base];
    float s  = v.x + v.y + v.z + v.w;
    float ss = v.x*v.x + v.y*v.y + v.z*v.z + v.w*v.w;
    #pragma unroll
    for (int o = 32; o; o >>= 1) { s += __shfl_xor(s, o); ss += __shfl_xor(ss, o); }
    float m = s * (1.0f/CC);
    float var = ss * (1.0f/CC) - m*m; if (var < 0.f) var = 0.f;
    float rs = rsqrtf(var + EPS_LN);
    float4 gg = *(const float4*)&g[lane*4];
    float4 bb = *(const float4*)&b[lane*4];
    v.x = (v.x - m)*rs*gg.x + bb.x;
    v.y = (v.y - m)*rs*gg.y + bb.y;
    v.z = (v.z - m)*rs*gg.z + bb.z;
    v.w = (v.w - m)*rs*gg.w + bb.w;
    *(float4*)&x[base] = v;
    ushort_t o4[4] = {f2bf(v.x), f2bf(v.y), f2bf(v.z), f2bf(v.w)};
    *(short4_t*)&outb[base] = *(short4_t*)o4;
}

// ---------------------------------------------------------------------------
// bf16 MFMA GEMM, token-major: D[m=token][n=outch] = act(A[m,:]·B[n,:] + bias[n] (+BN(res)))
// A [M',K] TM activations, B [N',K] weights, both k-contiguous bf16.
// out idx = m*ostride + n. grid (N'/128, M'/128).
#define FL_RELU  1
#define FL_BF16  2
#define FL_RESBN 4
__global__ __launch_bounds__(256) void k_gemm_mfma(
    const ushort_t* __restrict__ A, const ushort_t* __restrict__ B,
    const float* __restrict__ bias,
    const float* rx, const float* __restrict__ ms,
    const float* __restrict__ bng, const float* __restrict__ bnb,
    float* outf, ushort_t* __restrict__ outb,
    int K, int ostride, int flags)
{
    __shared__ ushort_t sA[128*48];
    __shared__ ushort_t sB[128*48];
    const int n0 = blockIdx.x * 128;   // out-channel tile
    const int m0 = blockIdx.y * 128;   // token tile
    const int tid = threadIdx.x;
    const int lane = tid & 63, wave = tid >> 6;
    const int wm = (wave & 1) * 64, wn = (wave >> 1) * 64;
    const int fr = lane >> 4, fc = lane & 15;

    floatx4 acc[4][4];
    #pragma unroll
    for (int i = 0; i < 4; i++)
        #pragma unroll
        for (int j = 0; j < 4; j++) acc[i][j] = (floatx4){0.f,0.f,0.f,0.f};

    for (int kc = 0; kc < K; kc += 32) {
        #pragma unroll
        for (int it = 0; it < 2; it++) {
            int task = tid + it*256;
            int row = task >> 2, ch = task & 3;
            *(short8*)&sA[row*48 + ch*8] =
                *(const short8*)&A[(size_t)(m0 + row)*K + kc + ch*8];
            *(short8*)&sB[row*48 + ch*8] =
                *(const short8*)&B[(size_t)(n0 + row)*K + kc + ch*8];
        }
        __syncthreads();
        short8 af[4], bfr[4];
        #pragma unroll
        for (int mi = 0; mi < 4; mi++)
            af[mi] = *(const short8*)&sA[(wm + mi*16 + fc)*48 + fr*8];
        #pragma unroll
        for (int ni = 0; ni < 4; ni++)
            bfr[ni] = *(const short8*)&sB[(wn + ni*16 + fc)*48 + fr*8];
        #pragma unroll
        for (int mi = 0; mi < 4; mi++)
            #pragma unroll
            for (int ni = 0; ni < 4; ni++)
                acc[mi][ni] = __builtin_amdgcn_mfma_f32_16x16x32_bf16(
                    af[mi], bfr[ni], acc[mi][ni], 0, 0, 0);
        __syncthreads();
    }
    // D layout per 16x16 tile: row(m)=(lane>>4)*4+r, col(n)=lane&15
    #pragma unroll
    for (int mi = 0; mi < 4; mi++) {
        #pragma unroll
        for (int ni = 0; ni < 4; ni++) {
            int n = n0 + wn + ni*16 + fc;
            float bn_ = bias[n];
            float bm = 0.f, bs = 0.f, bb2 = 0.f;
            if (flags & FL_RESBN) { bm = ms[n]; bs = ms[CC + n]*bng[n]; bb2 = bnb[n]; }
            #pragma unroll
            for (int r = 0; r < 4; r++) {
                int m = m0 + wm + mi*16 + fr*4 + r;
                size_t idx = (size_t)m*ostride + n;
                float val = acc[mi][ni][r] + bn_;
                if (flags & FL_RESBN) val += (rx[idx] - bm)*bs + bb2;
                if (flags & FL_RELU) val = fmaxf(val, 0.f);
                if (flags & FL_BF16) outb[idx] = f2bf(val);
                else                 outf[idx] = val;
            }
        }
    }
}

// ---------------------------------------------------------------------------
// Small fp32 GEMM (relay path)
__global__ __launch_bounds__(256) void k_sgemm(
    const float* __restrict__ W, const float* __restrict__ X,
    const float* __restrict__ bias, const float* __restrict__ res,
    float* __restrict__ out, int K, int OUT, int do_relu)
{
    __shared__ float sW[16][17];
    __shared__ float sX[16][17];
    int o0 = blockIdx.x*16, n0 = blockIdx.y*16;
    int tx = threadIdx.x, ty = threadIdx.y;
    int tid = ty*16 + tx;
    int cl = tid % 16, rl = tid / 16;
    float acc = 0.f;
    for (int kc = 0; kc < K; kc += 16) {
        sW[cl][rl] = W[(size_t)(o0 + rl)*K + kc + cl];
        sX[rl][cl] = (n0 + rl < NN) ? X[(size_t)(n0 + rl)*K + kc + cl] : 0.f;
        __syncthreads();
        #pragma unroll
        for (int kk = 0; kk < 16; kk++) acc += sW[kk][tx] * sX[ty][kk];
        __syncthreads();
    }
    int o = o0 + tx, n = n0 + ty;
    if (n < NN) {
        float val = acc + bias[o];
        if (res) val += res[(size_t)n*OUT + o];
        if (do_relu) val = fmaxf(val, 0.f);
        out[(size_t)n*OUT + o] = val;
    }
}

// ---------------------------------------------------------------------------
// tj attention, all token-major. qkv [nt][768] (q|k|v), ekv [nt][512] (ek|ev),
// rkv [n][512] f32, xln [nt][256] f32. out s1 [nt][256] f32.
__global__ __launch_bounds__(128) void k_attn_tj(
    const ushort_t* __restrict__ qkv, const ushort_t* __restrict__ ekv,
    const float* __restrict__ rkv, const float* __restrict__ xln,
    float* __restrict__ out)
{
    int t = threadIdx.x, h = blockIdx.x, n = blockIdx.y;
    int nt = n*TT + t;
    const ushort_t* qp = qkv + (size_t)nt*768 + h*32;
    const ushort_t* kp = qp + 256;
    const ushort_t* vp = qp + 512;
    const ushort_t* ep = ekv + (size_t)nt*512 + h*32;
    const float*    rp = rkv + n*512 + h*32;

    float qv[32];
    ld32(qp, qv);
    float s0 = 0.f, s1, s2 = 0.f, s3, s4 = 0.f;
    s1 = dot32(kp, qv);
    s3 = dot32(ep, qv);
    #pragma unroll
    for (int j = 0; j < 8; j++) {
        float4 rv4 = *(const float4*)&rp[j*4];
        s4 += qv[j*4]*rv4.x + qv[j*4+1]*rv4.y + qv[j*4+2]*rv4.z + qv[j*4+3]*rv4.w;
    }
    if (t > 0)    s0 = dot32(kp - 768, qv);
    if (t < TT-1) s2 = dot32(kp + 768, qv);

    s0 *= SCALE_F; s1 *= SCALE_F; s2 *= SCALE_F; s3 *= SCALE_F; s4 *= SCALE_F;
    float mx = fmaxf(fmaxf(fmaxf(s0, s1), fmaxf(s2, s3)), s4);
    float e0 = expf(s0-mx), e1 = expf(s1-mx), e2 = expf(s2-mx), e3 = expf(s3-mx), e4 = expf(s4-mx);
    float inv = 1.f/(e0+e1+e2+e3+e4);
    e0 *= inv; e1 *= inv; e2 *= inv; e3 *= inv; e4 *= inv;

    float av[32];
    #pragma unroll
    for (int d = 0; d < 32; d++) av[d] = 0.f;
    acc32(vp, e1, av);
    acc32(ep + 256, e3, av);
    if (t > 0)    acc32(vp - 768, e0, av);
    if (t < TT-1) acc32(vp + 768, e2, av);
    #pragma unroll
    for (int j = 0; j < 8; j++) {
        float4 rv4 = *(const float4*)&rp[256 + j*4];
        av[j*4] += e4*rv4.x; av[j*4+1] += e4*rv4.y; av[j*4+2] += e4*rv4.z; av[j*4+3] += e4*rv4.w;
    }
    const float* xp = xln + (size_t)nt*CC + h*32;
    float* op = out + (size_t)nt*CC + h*32;
    #pragma unroll
    for (int j = 0; j < 8; j++) {
        float4 xv = *(const float4*)&xp[j*4];
        float4 ov;
        ov.x = xv.x + av[j*4]; ov.y = xv.y + av[j*4+1];
        ov.z = xv.z + av[j*4+2]; ov.w = xv.w + av[j*4+3];
        *(float4*)&op[j*4] = ov;
    }
}

// ---------------------------------------------------------------------------
// BN stats over tokens, TM input. Stage 1: per-sequence partials.
__global__ __launch_bounds__(256) void k_bnstats_tm(const float* __restrict__ x,
    float* __restrict__ partial)
{
    __shared__ float lds[8][256];
    int w = threadIdx.x >> 6, lane = threadIdx.x & 63;
    size_t base = (size_t)blockIdx.x*TT*CC;
    float s[4] = {0,0,0,0}, ss[4] = {0,0,0,0};
    for (int tok = w; tok < TT; tok += 4) {
        float4 v = *(const float4*)&x[base + (size_t)tok*CC + lane*4];
        s[0] += v.x; s[1] += v.y; s[2] += v.z; s[3] += v.w;
        ss[0] += v.x*v.x; ss[1] += v.y*v.y; ss[2] += v.z*v.z; ss[3] += v.w*v.w;
    }
    #pragma unroll
    for (int j = 0; j < 4; j++) { lds[w][lane*4+j] = s[j]; lds[4+w][lane*4+j] = ss[j]; }
    __syncthreads();
    int c = threadIdx.x;
    float ps  = lds[0][c]+lds[1][c]+lds[2][c]+lds[3][c];
    float pss = lds[4][c]+lds[5][c]+lds[6][c]+lds[7][c];
    partial[blockIdx.x*512 + c] = ps;
    partial[blockIdx.x*512 + 256 + c] = pss;
}
// Stage 2: reduce 200 partials -> ms[c]=mean, ms[256+c]=rstd
__global__ __launch_bounds__(256) void k_bnfin(const float* __restrict__ partial,
    float* __restrict__ ms)
{
    int c = threadIdx.x;
    float s = 0.f, ss = 0.f;
    for (int b = 0; b < NN; b++) { s += partial[b*512 + c]; ss += partial[b*512 + 256 + c]; }
    float m = s / NT;
    float var = ss / NT - m*m; if (var < 0.f) var = 0.f;
    ms[c] = m; ms[CC + c] = rsqrtf(var + EPS_BN);
}

// BN apply, TM elementwise: f32 out (optional) + bf16 out
__global__ __launch_bounds__(256) void k_bn_apply_tm(const float* __restrict__ x,
    const float* __restrict__ ms, const float* __restrict__ g, const float* __restrict__ b,
    float* __restrict__ outf, ushort_t* __restrict__ outb, int leaky)
{
    size_t base = ((size_t)blockIdx.x*256 + threadIdx.x)*4;
    int c0 = (int)(base & (CC-1));
    float4 v  = *(const float4*)&x[base];
    float4 m4 = *(const float4*)&ms[c0];
    float4 r4 = *(const float4*)&ms[CC + c0];
    float4 g4 = *(const float4*)&g[c0];
    float4 b4 = *(const float4*)&b[c0];
    v.x = (v.x - m4.x)*r4.x*g4.x + b4.x;
    v.y = (v.y - m4.y)*r4.y*g4.y + b4.y;
    v.z = (v.z - m4.z)*r4.z*g4.z + b4.z;
    v.w = (v.w - m4.w)*r4.w*g4.w + b4.w;
    if (leaky) {
        v.x = v.x > 0.f ? v.x : SLOPE*v.x;
        v.y = v.y > 0.f ? v.y : SLOPE*v.y;
        v.z = v.z > 0.f ? v.z : SLOPE*v.z;
        v.w = v.w > 0.f ? v.w : SLOPE*v.w;
    }
    if (outf) *(float4*)&outf[base] = v;
    ushort_t o4[4] = {f2bf(v.x), f2bf(v.y), f2bf(v.z), f2bf(v.w)};
    *(short4_t*)&outb[base] = *(short4_t*)o4;
}

// final BN + leaky + transpose TM -> d_out [n][c][t]
__global__ __launch_bounds__(256) void k_bn_out_t(const float* __restrict__ x,
    const float* __restrict__ ms, const float* __restrict__ g, const float* __restrict__ b,
    float* __restrict__ out)
{
    __shared__ float tile[64][65];
    int nt0 = blockIdx.x*64, c0 = blockIdx.y*64;
    int w = threadIdx.x >> 6, lane = threadIdx.x & 63;
    int n = nt0 >> 7, t0 = nt0 & 127;
    #pragma unroll
    for (int it = 0; it < 16; it++) {
        int tok = it*4 + w, c = c0 + lane;
        float v = x[(size_t)(nt0 + tok)*CC + c];
        v = (v - ms[c])*ms[CC + c]*g[c] + b[c];
        v = v > 0.f ? v : SLOPE*v;
        tile[tok][lane] = v;
    }
    __syncthreads();
    #pragma unroll
    for (int it = 0; it < 16; it++) {
        int c_l = it*4 + w;
        out[(size_t)(n*CC + c0 + c_l)*TT + t0 + lane] = tile[lane][c_l];
    }
}

// BatchNorm over n only (relay path), x/out [N,C]
__global__ __launch_bounds__(64) void k_bn_relay(const float* __restrict__ x,
    float* __restrict__ out, const float* __restrict__ g, const float* __restrict__ b, int leaky)
{
    int c = blockIdx.x, tid = threadIdx.x;
    float s = 0.f, ss = 0.f;
    for (int n = tid; n < NN; n += 64) { float v = x[(size_t)n*CC + c]; s += v; ss += v*v; }
    for (int off = 32; off; off >>= 1) { s += __shfl_down(s, off); ss += __shfl_down(ss, off); }
    float S = __shfl(s, 0), SS = __shfl(ss, 0);
    float m = S / NN;
    float var = SS / NN - m*m; if (var < 0.f) var = 0.f;
    float rs = rsqrtf(var + EPS_BN);
    float gg = g[c]*rs, bb = b[c];
    for (int n = tid; n < NN; n += 64) {
        float v = (x[(size_t)n*CC + c] - m)*gg + bb;
        if (leaky) v = v > 0.f ? v : SLOPE*v;
        out[(size_t)n*CC + c] = v;
    }
}

// ---------------------------------------------------------------------------
// relay cross-attention; ykv TM f32 [nt][512] (k|v); rkvY [n][512]
__global__ __launch_bounds__(64) void k_attn_tr(
    const float* __restrict__ rq, const float* __restrict__ ykv,
    const float* __restrict__ rkvY, const float* __restrict__ relay,
    float* __restrict__ out)
{
    int h = blockIdx.x, n = blockIdx.y, tid = threadIdx.x;
    __shared__ float sc[LL1];
    __shared__ float red[64][33];
    float q0[32];
    const float* qp = rq + (size_t)n*CC + h*32;
    #pragma unroll
    for (int j = 0; j < 8; j++) {
        float4 v = *(const float4*)&qp[j*4];
        q0[j*4] = v.x; q0[j*4+1] = v.y; q0[j*4+2] = v.z; q0[j*4+3] = v.w;
    }
    for (int l = tid; l < LL1; l += 64) {
        const float* kp = (l == 0) ? (rkvY + n*512 + h*32)
                                   : (ykv + (size_t)(n*TT + l-1)*512 + h*32);
        float s = 0.f;
        #pragma unroll
        for (int j = 0; j < 8; j++) {
            float4 v = *(const float4*)&kp[j*4];
            s += q0[j*4]*v.x + q0[j*4+1]*v.y + q0[j*4+2]*v.z + q0[j*4+3]*v.w;
        }
        sc[l] = s * SCALE_F;
    }
    __syncthreads();
    float mx = -1e30f;
    for (int l = tid; l < LL1; l += 64) mx = fmaxf(mx, sc[l]);
    for (int off = 32; off; off >>= 1) mx = fmaxf(mx, __shfl_xor(mx, off));
    float sum = 0.f;
    for (int l = tid; l < LL1; l += 64) { float e = expf(sc[l]-mx); sc[l] = e; sum += e; }
    for (int off = 32; off; off >>= 1) sum += __shfl_xor(sum, off);
    __syncthreads();
    float av[32];
    #pragma unroll
    for (int d = 0; d < 32; d++) av[d] = 0.f;
    for (int l = tid; l < LL1; l += 64) {
        float e = sc[l];
        const float* vp = (l == 0) ? (rkvY + n*512 + 256 + h*32)
                                   : (ykv + (size_t)(n*TT + l-1)*512 + 256 + h*32);
        #pragma unroll
        for (int j = 0; j < 8; j++) {
            float4 v = *(const float4*)&vp[j*4];
            av[j*4] += e*v.x; av[j*4+1] += e*v.y; av[j*4+2] += e*v.z; av[j*4+3] += e*v.w;
        }
    }
    #pragma unroll
    for (int d = 0; d < 32; d++) red[tid][d] = av[d];
    __syncthreads();
    if (tid < 32) {
        float a = 0.f;
        for (int k = 0; k < 64; k++) a += red[k][tid];
        a /= sum;
        int idx = n*CC + h*32 + tid;
        out[idx] = relay[idx] + a;
    }
}

// ---------------------------------------------------------------------------
extern "C" void kernel_launch(void* const* d_in, const int* in_sizes, int n_in,
                              void* d_out, int out_size, void* d_ws, size_t ws_size,
                              hipStream_t stream)
{
    const float* data    = (const float*)d_in[0];
    const float* ln_g    = (const float*)d_in[1];
    const float* ln_b    = (const float*)d_in[2];
    const float* tj_wq   = (const float*)d_in[3];
    const float* tj_bq   = (const float*)d_in[4];
    const float* tj_wk   = (const float*)d_in[5];
    const float* tj_bk   = (const float*)d_in[6];
    const float* tj_wv   = (const float*)d_in[7];
    const float* tj_bv   = (const float*)d_in[8];
    const float* tj_bn_g = (const float*)d_in[9];
    const float* tj_bn_b = (const float*)d_in[10];
    const float* tj_w1   = (const float*)d_in[11];
    const float* tj_b1   = (const float*)d_in[12];
    const float* tj_w2   = (const float*)d_in[13];
    const float* tj_b2   = (const float*)d_in[14];
    const float* tj_fbn_g= (const float*)d_in[15];
    const float* tj_fbn_b= (const float*)d_in[16];
    const float* tr_wq   = (const float*)d_in[17];
    const float* tr_bq   = (const float*)d_in[18];
    const float* tr_wk   = (const float*)d_in[19];
    const float* tr_bk   = (const float*)d_in[20];
    const float* tr_wv   = (const float*)d_in[21];
    const float* tr_bv   = (const float*)d_in[22];
    const float* tr_bn_g = (const float*)d_in[23];
    const float* tr_bn_b = (const float*)d_in[24];
    const float* tr_w1   = (const float*)d_in[25];
    const float* tr_b1   = (const float*)d_in[26];
    const float* tr_w2   = (const float*)d_in[27];
    const float* tr_b2   = (const float*)d_in[28];
    const float* tr_fbn_g= (const float*)d_in[29];
    const float* tr_fbn_b= (const float*)d_in[30];

    const size_t SZ = (size_t)NT*CC;     // 6,553,600
    const size_t SZ_NC = (size_t)NN*CC;

    // ws ~158 MB (R3's 167 passed)
    float* ws = (float*)d_ws;
    size_t off = 0;
    auto alloc = [&](size_t nf) { float* p = ws + off; off += nf; return p; };
    float*    nodesf  = alloc(SZ);          // TM f32; LN in-place (holds xln)
    float*    sbuf    = alloc(SZ);          // TM f32: s1 / s1b (FFN2 in-place)
    float*    P1      = alloc(SZ*5/2);      // qkv(1.5)+ekv(1.0) bf16 | h(2.0) bf16 | ykv(2.0) f32
    ushort_t* xs_bf   = (ushort_t*)alloc(SZ/2);  // xln_bf -> s2_bf -> nodes_bf (TM)
    ushort_t* embs_bf = (ushort_t*)alloc(SZ/2);  // TM, persists
    float* partial = alloc((size_t)NN*512);
    float* msA    = alloc(2*CC);
    float* msB    = alloc(2*CC);
    float* relayA = alloc(SZ_NC);
    float* relayB = alloc(SZ_NC);
    float* rkv    = alloc(2*SZ_NC);
    float* rkvY   = alloc(2*SZ_NC);
    float* rq_    = alloc(SZ_NC);
    float* ret0   = alloc(SZ_NC);
    float* rret   = alloc(SZ_NC);
    float* ro     = alloc(SZ_NC);
    float* rh     = alloc((size_t)NN*DFFF);
    ushort_t* wqkv_bf  = (ushort_t*)alloc((size_t)ITER*768*CC/2);
    ushort_t* wkvtr_bf = (ushort_t*)alloc((size_t)ITER*512*CC/2);
    ushort_t* w1_bf    = (ushort_t*)alloc((size_t)ITER*DFFF*CC/2);
    ushort_t* w2_bf    = (ushort_t*)alloc((size_t)ITER*DFFF*CC/2);
    float* wkvtj_f = alloc((size_t)ITER*512*CC);
    float* wkvtr_f = alloc((size_t)ITER*512*CC);
    float* bqkv    = alloc((size_t)ITER*768);
    float* bkvtr   = alloc((size_t)ITER*512);
    (void)ws_size; (void)in_sizes; (void)n_in; (void)out_size;

    ushort_t* qkv_tm = (ushort_t*)P1;           // [nt][768] bf16
    ushort_t* ekv_tm = qkv_tm + 3*SZ;           // [nt][512] bf16
    ushort_t* h_us   = (ushort_t*)P1;           // [nt][1024] bf16 (after attn)
    float*    ykv_f  = P1;                      // [nt][512] f32 (after FFN2)

    const int TCC = ITER*CC*CC, TFF = ITER*DFFF*CC;
    k_cast2<<<(TCC+255)/256, 256, 0, stream>>>(tj_wq, wqkv_bf,          65536, 196608, TCC);
    k_cast2<<<(TCC+255)/256, 256, 0, stream>>>(tj_wk, wqkv_bf +  65536, 65536, 196608, TCC);
    k_cast2<<<(TCC+255)/256, 256, 0, stream>>>(tj_wv, wqkv_bf + 131072, 65536, 196608, TCC);
    k_cast2<<<(TCC+255)/256, 256, 0, stream>>>(tr_wk, wkvtr_bf,         65536, 131072, TCC);
    k_cast2<<<(TCC+255)/256, 256, 0, stream>>>(tr_wv, wkvtr_bf + 65536, 65536, 131072, TCC);
    k_cast2<<<(TFF+255)/256, 256, 0, stream>>>(tj_w1, w1_bf, TFF, TFF, TFF);
    k_cast2<<<(TFF+255)/256, 256, 0, stream>>>(tj_w2, w2_bf, TFF, TFF, TFF);
    k_copy2<<<(ITER*256+255)/256, 256, 0, stream>>>(tj_bq, bqkv,       256, 768, ITER*256);
    k_copy2<<<(ITER*256+255)/256, 256, 0, stream>>>(tj_bk, bqkv + 256, 256, 768, ITER*256);
    k_copy2<<<(ITER*256+255)/256, 256, 0, stream>>>(tj_bv, bqkv + 512, 256, 768, ITER*256);
    k_copy2<<<(ITER*256+255)/256, 256, 0, stream>>>(tr_bk, bkvtr,      256, 512, ITER*256);
    k_copy2<<<(ITER*256+255)/256, 256, 0, stream>>>(tr_bv, bkvtr+256,  256, 512, ITER*256);
    k_copy2<<<(TCC+255)/256, 256, 0, stream>>>(tj_wk, wkvtj_f,         65536, 131072, TCC);
    k_copy2<<<(TCC+255)/256, 256, 0, stream>>>(tj_wv, wkvtj_f + 65536, 65536, 131072, TCC);
    k_copy2<<<(TCC+255)/256, 256, 0, stream>>>(tr_wk, wkvtr_f,         65536, 131072, TCC);
    k_copy2<<<(TCC+255)/256, 256, 0, stream>>>(tr_wv, wkvtr_f + 65536, 65536, 131072, TCC);

    k_embed<<<dim3(8, NN), 128, 0, stream>>>(data, nodesf, embs_bf, relayA);

    float* relay = relayA;
    float* relay_next = relayB;
    dim3 sb16(16, 16);

    for (int i = 0; i < ITER; i++) {
        const size_t wo768 = (size_t)i*768*CC;
        const size_t wo512 = (size_t)i*512*CC;
        const size_t woff  = (size_t)i*DFFF*CC;

        k_layernorm<<<NT/4, 256, 0, stream>>>(nodesf, xs_bf, ln_g + i*CC, ln_b + i*CC);

        // qkv: [nt][768] bf16
        k_gemm_mfma<<<dim3(6, NT/128), 256, 0, stream>>>(
            xs_bf, wqkv_bf + wo768, bqkv + i*768, nullptr, nullptr, nullptr, nullptr,
            nullptr, qkv_tm, CC, 768, FL_BF16);
        // ekv: [nt][512] bf16 (weight rows 256..767)
        k_gemm_mfma<<<dim3(4, NT/128), 256, 0, stream>>>(
            embs_bf, wqkv_bf + wo768 + 65536, bqkv + i*768 + 256, nullptr, nullptr, nullptr, nullptr,
            nullptr, ekv_tm, CC, 512, FL_BF16);
        // relay k|v f32 [n][512]
        k_sgemm<<<dim3(32, (NN+15)/16), sb16, 0, stream>>>(
            wkvtj_f + wo512, relay, bqkv + i*768 + 256, nullptr, rkv, CC, 512, 0);

        k_attn_tj<<<dim3(NHH, NN), 128, 0, stream>>>(qkv_tm, ekv_tm, rkv, nodesf, sbuf);

        k_bnstats_tm<<<NN, 256, 0, stream>>>(sbuf, partial);
        k_bnfin<<<1, 256, 0, stream>>>(partial, msA);
        // BN1 apply -> s2_bf only (FFN2 recomputes BN1(s1) in epilogue)
        k_bn_apply_tm<<<SZ/1024, 256, 0, stream>>>(
            sbuf, msA, tj_bn_g + i*CC, tj_bn_b + i*CC, nullptr, xs_bf, 0);

        // FFN1: h = relu(W1*s2+b1), [nt][1024] bf16
        k_gemm_mfma<<<dim3(8, NT/128), 256, 0, stream>>>(
            xs_bf, w1_bf + woff, tj_b1 + i*DFFF, nullptr, nullptr, nullptr, nullptr,
            nullptr, h_us, CC, DFFF, FL_RELU | FL_BF16);
        // FFN2: sbuf = W2*h + b2 + BN1(sbuf)   (in-place, per-thread idx safe)
        k_gemm_mfma<<<dim3(2, NT/128), 256, 0, stream>>>(
            h_us, w2_bf + woff, tj_b2 + i*CC, sbuf, msA, tj_bn_g + i*CC, tj_bn_b + i*CC,
            sbuf, nullptr, DFFF, CC, FL_RESBN);

        k_bnstats_tm<<<NN, 256, 0, stream>>>(sbuf, partial);
        k_bnfin<<<1, 256, 0, stream>>>(partial, msB);
        if (i == ITER-1) {
            k_bn_out_t<<<dim3(NT/64, CC/64), 256, 0, stream>>>(
                sbuf, msB, tj_fbn_g + i*CC, tj_fbn_b + i*CC, (float*)d_out);
            break;   // last relay update is dead code
        }
        // nodes = leaky(BN2(sbuf)) -> nodesf f32 + xs_bf bf16
        k_bn_apply_tm<<<SZ/1024, 256, 0, stream>>>(
            sbuf, msB, tj_fbn_g + i*CC, tj_fbn_b + i*CC, nodesf, xs_bf, 1);

        // relay path: ykv = W_kv^tr * nodes, [nt][512] f32
        k_gemm_mfma<<<dim3(4, NT/128), 256, 0, stream>>>(
            xs_bf, wkvtr_bf + wo512, bkvtr + i*512, nullptr, nullptr, nullptr, nullptr,
            ykv_f, nullptr, CC, 512, 0);
        k_sgemm<<<dim3(16, (NN+15)/16), sb16, 0, stream>>>(
            tr_wq + (size_t)i*CC*CC, relay, tr_bq + i*CC, nullptr, rq_, CC, CC, 0);
        k_sgemm<<<dim3(32, (NN+15)/16), sb16, 0, stream>>>(
            wkvtr_f + wo512, relay, bkvtr + i*512, nullptr, rkvY, CC, 512, 0);

        k_attn_tr<<<dim3(NHH, NN), 64, 0, stream>>>(rq_, ykv_f, rkvY, relay, ret0);
        k_bn_relay<<<CC, 64, 0, stream>>>(ret0, rret, tr_bn_g + i*CC, tr_bn_b + i*CC, 0);

        k_sgemm<<<dim3(DFFF/16, (NN+15)/16), sb16, 0, stream>>>(
            tr_w1 + woff, rret, tr_b1 + i*DFFF, nullptr, rh, CC, DFFF, 1);
        k_sgemm<<<dim3(16, (NN+15)/16), sb16, 0, stream>>>(
            tr_w2 + woff, rh, tr_b2 + i*CC, rret, ro, DFFF, CC, 0);
        k_bn_relay<<<CC, 64, 0, stream>>>(ro, relay_next, tr_fbn_g + i*CC, tr_fbn_b + i*CC, 1);

        float* tmp = relay; relay = relay_next; relay_next = tmp;
    }
}